// Round 6
// baseline (401.569 us; speedup 1.0000x reference)
//
#include <hip/hip_runtime.h>
#include <hip/hip_bf16.h>

// Performer (ORF linear attention) + out-proj + residual + LayerNorm.
// Round 6: latency-bound passC fixed — kvT layout (passA direct-stores),
// Spref read direct from global, zpref as synthesized fragment, Q in regs.

typedef float f4 __attribute__((ext_vector_type(4)));
typedef __attribute__((ext_vector_type(8))) short bf16x8;
typedef __attribute__((ext_vector_type(4))) float f32x4;
typedef unsigned short u16x4 __attribute__((ext_vector_type(4)));
typedef unsigned short u16x8 __attribute__((ext_vector_type(8)));

#define B_  4
#define L_  2048
#define H_  16
#define D_  64
#define DM_ 1024
#define R_  256
#define C_  64
#define NC_ (L_ / C_)
#define M_  (B_ * L_)
#define M2_ (M_ * H_)

static __device__ __forceinline__ unsigned short f2bu(float x) {
    __hip_bfloat16 h = __float2bfloat16(x);
    return *(unsigned short*)&h;
}
static __device__ __forceinline__ float bu2f(unsigned short u) {
    union { unsigned int i; float f; } c; c.i = ((unsigned int)u) << 16; return c.f;
}

typedef __attribute__((address_space(3))) void lds_void_t;
typedef __attribute__((address_space(1))) const void gvoid_t;
static __device__ __forceinline__ void gload16(const void* g, void* l) {
    __builtin_amdgcn_global_load_lds((gvoid_t*)g, (lds_void_t*)l, 16, 0, 0);
}

// ---------------------------------------------------------------------------
// fp32 -> bf16 cast, 4 elements/thread
// ---------------------------------------------------------------------------
__launch_bounds__(256)
__global__ void cvt_bf16(const float* __restrict__ in, unsigned short* __restrict__ out, int n4) {
    int i = blockIdx.x * 256 + threadIdx.x;
    if (i < n4) {
        f4 v = *(const f4*)&in[(size_t)i * 4];
        ushort4 o;
        o.x = f2bu(v[0]); o.y = f2bu(v[1]); o.z = f2bu(v[2]); o.w = f2bu(v[3]);
        *(ushort4*)&out[(size_t)i * 4] = o;
    }
}

// ---------------------------------------------------------------------------
// C[M,N] = A[M,K] @ B[N,K]^T, bf16 MFMA, 128x128 tile.
// mode 0: fp32 out; mode 1: fp32 out + fp32 resid; mode 2: bf16 out.
// ---------------------------------------------------------------------------
__launch_bounds__(256)
__global__ void gemm_mfma(const unsigned short* __restrict__ A,
                          const unsigned short* __restrict__ Bw,
                          const float* __restrict__ resid,
                          float* __restrict__ Cf, unsigned short* __restrict__ Cb,
                          int M, int N, int K, int mode) {
    __shared__ unsigned short Asl[128 * 32];
    __shared__ unsigned short Bsl[128 * 32];
    const int t = threadIdx.x;
    const int lane = t & 63, w = t >> 6;
    const int wr = w >> 1, wc = w & 1;
    const int row0 = blockIdx.y * 128, col0 = blockIdx.x * 128;
    const int sr0 = t >> 2, sk0 = (t & 3) * 8;
    const int lg = lane >> 4, lr = lane & 15;

    f32x4 acc[4][4] = {};
    for (int kk = 0; kk < K; kk += 32) {
        __syncthreads();
        gload16(&A [(size_t)(row0 + sr0)      * K + kk + sk0], &Asl[t * 8]);
        gload16(&A [(size_t)(row0 + sr0 + 64) * K + kk + sk0], &Asl[(t + 256) * 8]);
        gload16(&Bw[(size_t)(col0 + sr0)      * K + kk + sk0], &Bsl[t * 8]);
        gload16(&Bw[(size_t)(col0 + sr0 + 64) * K + kk + sk0], &Bsl[(t + 256) * 8]);
        __syncthreads();

        bf16x8 af[4], bfr[4];
#pragma unroll
        for (int m = 0; m < 4; ++m)
            af[m] = *(const bf16x8*)&Asl[(wr * 64 + m * 16 + lr) * 32 + lg * 8];
#pragma unroll
        for (int n = 0; n < 4; ++n)
            bfr[n] = *(const bf16x8*)&Bsl[(wc * 64 + n * 16 + lr) * 32 + lg * 8];
#pragma unroll
        for (int m = 0; m < 4; ++m)
#pragma unroll
            for (int n = 0; n < 4; ++n)
                acc[m][n] = __builtin_amdgcn_mfma_f32_16x16x32_bf16(af[m], bfr[n], acc[m][n], 0, 0, 0);
    }
#pragma unroll
    for (int m = 0; m < 4; ++m)
#pragma unroll
        for (int n = 0; n < 4; ++n) {
#pragma unroll
            for (int i = 0; i < 4; ++i) {
                int r  = row0 + wr * 64 + m * 16 + lg * 4 + i;
                int cc = col0 + wc * 64 + n * 16 + lr;
                size_t off = (size_t)r * N + cc;
                float v = acc[m][n][i];
                if (mode == 2) {
                    Cb[off] = f2bu(v);
                } else {
                    if (mode == 1) v += resid[off];
                    Cf[off] = v;
                }
            }
        }
}

// ---------------------------------------------------------------------------
// feat_mfma: out[m,r] = bf16( sqrt(2/R)*cos( dot(X[m,:64], omega[r,:64]) + b[r] ) )
// ---------------------------------------------------------------------------
__launch_bounds__(256)
__global__ void feat_mfma(const unsigned short* __restrict__ X,
                          const unsigned short* __restrict__ om,
                          const float* __restrict__ bvec,
                          unsigned short* __restrict__ out) {
    __shared__ unsigned short Xs[2 * 64 * 32];    // 8 KB
    __shared__ unsigned short Os[2 * 256 * 32];   // 32 KB
    __shared__ unsigned short Rs[64][264];        // 33 KB repack
    const int t = threadIdx.x;
    const int lane = t & 63, w = t >> 6;
    const int lg = lane >> 4, lr = lane & 15;
    const int m0 = blockIdx.x * 64;

#pragma unroll
    for (int i = 0; i < 2; ++i) {
        int cch = i * 256 + t;
        int ks = cch >> 8, row = (cch >> 2) & 63, sub = cch & 3;
        gload16(&X[(size_t)(m0 + row) * 64 + ks * 32 + sub * 8], &Xs[cch * 8]);
    }
#pragma unroll
    for (int i = 0; i < 8; ++i) {
        int cch = i * 256 + t;
        int ks = cch >> 10, r = (cch >> 2) & 255, sub = cch & 3;
        gload16(&om[(size_t)r * 64 + ks * 32 + sub * 8], &Os[cch * 8]);
    }
    __syncthreads();

    f32x4 acc[4][4] = {};
#pragma unroll
    for (int ks = 0; ks < 2; ++ks) {
        bf16x8 af[4], bfr[4];
#pragma unroll
        for (int m = 0; m < 4; ++m)
            af[m] = *(const bf16x8*)&Xs[ks * 2048 + (m * 16 + lr) * 32 + lg * 8];
#pragma unroll
        for (int n = 0; n < 4; ++n)
            bfr[n] = *(const bf16x8*)&Os[ks * 8192 + (w * 64 + n * 16 + lr) * 32 + lg * 8];
#pragma unroll
        for (int m = 0; m < 4; ++m)
#pragma unroll
            for (int n = 0; n < 4; ++n)
                acc[m][n] = __builtin_amdgcn_mfma_f32_16x16x32_bf16(af[m], bfr[n], acc[m][n], 0, 0, 0);
    }

    const float scale = 0.08838834764831845f;  // sqrt(2/256)
#pragma unroll
    for (int n = 0; n < 4; ++n) {
        const int col = w * 64 + n * 16 + lr;
        const float bb = bvec[col];
#pragma unroll
        for (int m = 0; m < 4; ++m)
#pragma unroll
            for (int ii = 0; ii < 4; ++ii)
                Rs[m * 16 + lg * 4 + ii][col] = f2bu(scale * __cosf(acc[m][n][ii] + bb));
    }
    __syncthreads();
#pragma unroll
    for (int i = 0; i < 8; ++i) {
        int cch = i * 256 + t;
        int row = cch >> 5, colc = (cch & 31) * 8;
        u16x8 vv = *(const u16x8*)&Rs[row][colc];
        *(u16x8*)&out[(size_t)(m0 + row) * 256 + colc] = vv;
    }
}

// ---------------------------------------------------------------------------
// passA (MFMA): kvT[bh][c][d][r] = sum_l kp[l][r]*vb[l][d] (bf16), ksum[r].
// A-op = KP^T rows (r), B-op = V^T rows (d) -> out (r,d): 4 consecutive r per
// thread -> direct coalesced u16x4 global stores, no repack.
// ---------------------------------------------------------------------------
__launch_bounds__(256)
__global__ void passA_mfma(const unsigned short* __restrict__ kp, const unsigned short* __restrict__ vb,
                           unsigned short* __restrict__ kvT, float* __restrict__ ksum) {
    __shared__ __align__(16) unsigned short KPt[256][72];  // [r][l]
    __shared__ __align__(16) unsigned short Vt[64][72];    // [d][l]
    const int c = blockIdx.x, h = blockIdx.y, bz = blockIdx.z;
    const int t = threadIdx.x;
    const int lane = t & 63, w = t >> 6;
    const int lg = lane >> 4, lr = lane & 15;
    const int l0 = c * C_;
    const int bh = bz * H_ + h;

    {   // stage KP^T
        const int l4 = (t & 15) * 4, rs = (t >> 4) * 16;
        u16x8 row[4][2];
#pragma unroll
        for (int i = 0; i < 4; ++i) {
            const unsigned short* src = &kp[((size_t)(bz * L_ + l0 + l4 + i) * H_ + h) * R_ + rs];
            row[i][0] = *(const u16x8*)src;
            row[i][1] = *(const u16x8*)(src + 8);
        }
#pragma unroll
        for (int q = 0; q < 16; ++q) {
            u16x4 pk = { row[0][q >> 3][q & 7], row[1][q >> 3][q & 7],
                         row[2][q >> 3][q & 7], row[3][q >> 3][q & 7] };
            *(u16x4*)&KPt[rs + q][l4] = pk;
        }
    }
    {   // stage V^T (bf16 pass-through)
        const int d4 = (t & 15) * 4, ls = (t >> 4) * 4;
        u16x4 x[4];
#pragma unroll
        for (int i = 0; i < 4; ++i)
            x[i] = *(const u16x4*)&vb[(size_t)(bz * L_ + l0 + ls + i) * DM_ + h * 64 + d4];
#pragma unroll
        for (int q = 0; q < 4; ++q) {
            u16x4 pk = { x[0][q], x[1][q], x[2][q], x[3][q] };
            *(u16x4*)&Vt[d4 + q][ls] = pk;
        }
    }
    __syncthreads();

    // A = KPt (wave w owns r in [64w, 64w+64)), B = Vt (d = 0..63)
    f32x4 acc[4][4] = {};
#pragma unroll
    for (int ks = 0; ks < 2; ++ks) {
        bf16x8 af[4], bfr[4];
#pragma unroll
        for (int m = 0; m < 4; ++m)
            af[m] = *(const bf16x8*)&KPt[64 * w + 16 * m + lr][ks * 32 + lg * 8];
#pragma unroll
        for (int n = 0; n < 4; ++n)
            bfr[n] = *(const bf16x8*)&Vt[16 * n + lr][ks * 32 + lg * 8];
#pragma unroll
        for (int m = 0; m < 4; ++m)
#pragma unroll
            for (int n = 0; n < 4; ++n)
                acc[m][n] = __builtin_amdgcn_mfma_f32_16x16x32_bf16(af[m], bfr[n], acc[m][n], 0, 0, 0);
    }
    // store kvT[d][r]: thread holds (r = 64w+16m+lg*4+[0..3], d = 16n+lr)
    size_t sbase = ((size_t)(bh * NC_ + c)) * 64 * R_;
#pragma unroll
    for (int n = 0; n < 4; ++n)
#pragma unroll
        for (int m = 0; m < 4; ++m) {
            int d = 16 * n + lr;
            int r = 64 * w + 16 * m + lg * 4;
            u16x4 pk = { f2bu(acc[m][n][0]), f2bu(acc[m][n][1]),
                         f2bu(acc[m][n][2]), f2bu(acc[m][n][3]) };
            *(u16x4*)&kvT[sbase + (size_t)d * R_ + r] = pk;
        }
    {
        float s = 0.f;
#pragma unroll
        for (int j = 0; j < 8; ++j) {
            u16x8 vv = *(const u16x8*)&KPt[t][j * 8];
#pragma unroll
            for (int q = 0; q < 8; ++q) s += bu2f(vv[q]);
        }
        ksum[((size_t)(bh * NC_ + c)) * R_ + t] = s;
    }
}

// ---------------------------------------------------------------------------
// passB: exclusive prefix over chunks of kvT ([bh][c][d][r]) and ksum.
// grid (64, H, B): bx = d; threads = r (coalesced).
// ---------------------------------------------------------------------------
__launch_bounds__(256)
__global__ void passB_chain(unsigned short* __restrict__ kvT, float* __restrict__ ksum) {
    const int d = blockIdx.x, h = blockIdx.y, bz = blockIdx.z;
    const int t = threadIdx.x;
    const int bh = bz * H_ + h;
    size_t base = ((size_t)bh * NC_ * 64 + d) * R_ + t;
    const size_t cstride = (size_t)64 * R_;
    float run = 0.f;
    for (int c = 0; c < NC_; ++c) {
        size_t idx = base + (size_t)c * cstride;
        float tmp = bu2f(kvT[idx]);
        kvT[idx] = f2bu(run);
        run += tmp;
    }
    if (d == 0) {
        float rz = 0.f;
        for (int c = 0; c < NC_; ++c) {
            size_t idx = ((size_t)bh * NC_ + c) * R_ + t;
            float tmp = ksum[idx];
            ksum[idx] = rz;
            rz += tmp;
        }
    }
}

// ---------------------------------------------------------------------------
// passC (MFMA): A = mask(QP@KP^T) -> As LDS; out = (A@V + QP@Spref)/den.
// Spref B-fragments read DIRECT from global kvT [d][r]; zpref as a
// register-synthesized broadcast fragment; den via ones-row of Vt + shfl.
// LDS = Vt (11.5 KB) + As (9 KB).
// ---------------------------------------------------------------------------
__launch_bounds__(256)
__global__ void passC_mfma(const unsigned short* __restrict__ qp, const unsigned short* __restrict__ kp,
                           const unsigned short* __restrict__ vb, const unsigned short* __restrict__ kvT,
                           const float* __restrict__ zpref, unsigned short* __restrict__ attnb) {
    __shared__ __align__(16) unsigned short Vt[80][72];   // [d][l], row64=ones, 65..79=0
    __shared__ __align__(16) unsigned short As[64][72];   // masked scores

    const int c = blockIdx.x, h = blockIdx.y, bz = blockIdx.z;
    const int t = threadIdx.x;
    const int lane = t & 63, w = t >> 6;
    const int lg = lane >> 4, lr = lane & 15;
    const int l0 = c * C_;
    const int bh = bz * H_ + h;

    {   // stage V^T (bf16 pass-through)
        const int d4 = (t & 15) * 4, ls = (t >> 4) * 4;
        u16x4 x[4];
#pragma unroll
        for (int i = 0; i < 4; ++i)
            x[i] = *(const u16x4*)&vb[(size_t)(bz * L_ + l0 + ls + i) * DM_ + h * 64 + d4];
#pragma unroll
        for (int q = 0; q < 4; ++q) {
            u16x4 pk = { x[0][q], x[1][q], x[2][q], x[3][q] };
            *(u16x4*)&Vt[d4 + q][ls] = pk;
        }
    }
    if (t < 16) {
        u16x4 ones = { 0x3F80, 0x3F80, 0x3F80, 0x3F80 };
        *(u16x4*)&Vt[64][t * 4] = ones;
    }
    for (int i = t; i < 15 * 72; i += 256) Vt[65 + i / 72][i % 72] = 0;

    // Q fragments in registers (reused by scores and Spref phases)
    const size_t qrow = ((size_t)(bz * L_ + l0 + 16 * w + lr) * H_ + h) * R_;
    bf16x8 aq[8];
#pragma unroll
    for (int ks = 0; ks < 8; ++ks) aq[ks] = *(const bf16x8*)&qp[qrow + ks * 32 + lg * 8];

    // ---- scores ----
    f32x4 sacc[4] = {};
#pragma unroll
    for (int ks = 0; ks < 8; ++ks) {
#pragma unroll
        for (int n = 0; n < 4; ++n) {
            bf16x8 bk = *(const bf16x8*)&kp[((size_t)(bz * L_ + l0 + 16 * n + lr) * H_ + h) * R_ + ks * 32 + lg * 8];
            sacc[n] = __builtin_amdgcn_mfma_f32_16x16x32_bf16(aq[ks], bk, sacc[n], 0, 0, 0);
        }
    }
#pragma unroll
    for (int n = 0; n < 4; ++n)
#pragma unroll
        for (int ii = 0; ii < 4; ++ii) {
            int i_loc = 16 * w + lg * 4 + ii;
            int j_loc = 16 * n + lr;
            As[i_loc][j_loc] = (j_loc <= i_loc) ? f2bu(sacc[n][ii]) : (unsigned short)0;
        }

    // ---- Spref phase (global direct + regs; overlaps As write latency) ----
    f32x4 oacc[4] = {};
    f32x4 dacc = {};
    const size_t sbase = ((size_t)(bh * NC_ + c)) * 64 * R_;
    const size_t zbase = ((size_t)(bh * NC_ + c)) * R_;
#pragma unroll
    for (int ks = 0; ks < 8; ++ks) {
#pragma unroll
        for (int n = 0; n < 4; ++n) {
            bf16x8 bs = *(const bf16x8*)&kvT[sbase + (size_t)(16 * n + lr) * R_ + ks * 32 + lg * 8];
            oacc[n] = __builtin_amdgcn_mfma_f32_16x16x32_bf16(aq[ks], bs, oacc[n], 0, 0, 0);
        }
        f4 z0 = *(const f4*)&zpref[zbase + ks * 32 + lg * 8];
        f4 z1 = *(const f4*)&zpref[zbase + ks * 32 + lg * 8 + 4];
        u16x8 zu = { f2bu(z0[0]), f2bu(z0[1]), f2bu(z0[2]), f2bu(z0[3]),
                     f2bu(z1[0]), f2bu(z1[1]), f2bu(z1[2]), f2bu(z1[3]) };
        dacc = __builtin_amdgcn_mfma_f32_16x16x32_bf16(*(bf16x8*)&zu, *(bf16x8*)&zu, dacc, 0, 0, 0);
        // NOTE: A-operand must be aq[ks]; fixed below (kept for clarity)
        // (see corrected line)
    }
    // The loop above needs A=aq: redo dacc correctly (compiler folds dead mfma? keep correct only)
    // -- corrected dacc computed here --
    dacc = f32x4{0.f, 0.f, 0.f, 0.f};
#pragma unroll
    for (int ks = 0; ks < 8; ++ks) {
        f4 z0 = *(const f4*)&zpref[zbase + ks * 32 + lg * 8];
        f4 z1 = *(const f4*)&zpref[zbase + ks * 32 + lg * 8 + 4];
        u16x8 zu = { f2bu(z0[0]), f2bu(z0[1]), f2bu(z0[2]), f2bu(z0[3]),
                     f2bu(z1[0]), f2bu(z1[1]), f2bu(z1[2]), f2bu(z1[3]) };
        dacc = __builtin_amdgcn_mfma_f32_16x16x32_bf16(aq[ks], *(bf16x8*)&zu, dacc, 0, 0, 0);
    }
    __syncthreads();

    // ---- A@[V | ones] from LDS ----
    f32x4 racc = {};   // rowsum via ones column (valid at lr==0)
#pragma unroll
    for (int ks = 0; ks < 2; ++ks) {
        bf16x8 aa = *(const bf16x8*)&As[16 * w + lr][ks * 32 + lg * 8];
#pragma unroll
        for (int n = 0; n < 4; ++n) {
            bf16x8 bv = *(const bf16x8*)&Vt[16 * n + lr][ks * 32 + lg * 8];
            oacc[n] = __builtin_amdgcn_mfma_f32_16x16x32_bf16(aa, bv, oacc[n], 0, 0, 0);
        }
        bf16x8 b4 = *(const bf16x8*)&Vt[64 + lr][ks * 32 + lg * 8];
        racc = __builtin_amdgcn_mfma_f32_16x16x32_bf16(aa, b4, racc, 0, 0, 0);
    }

    // ---- epilogue ----
#pragma unroll
    for (int ii = 0; ii < 4; ++ii) {
        float rs_ = __shfl(racc[ii], lane & 48, 64);   // lr==0 lane holds rowsum
        float den = rs_ + dacc[ii];
        float inv = 1.f / (fmaxf(den, 1e-6f) + 1e-6f);
#pragma unroll
        for (int n = 0; n < 4; ++n)
            attnb[(size_t)(bz * L_ + l0 + 16 * w + lg * 4 + ii) * DM_ + h * 64 + 16 * n + lr] =
                f2bu(oacc[n][ii] * inv);
    }
}

// ---------------------------------------------------------------------------
// In-place row LayerNorm over last dim (1024), eps=1e-5.
// ---------------------------------------------------------------------------
__launch_bounds__(256)
__global__ void ln_kernel(float* __restrict__ io, const float* __restrict__ gamma,
                          const float* __restrict__ beta) {
    __shared__ float wsum[4], wsum2[4];
    const int row = blockIdx.x;
    const int t = threadIdx.x;
    f4 x = *(const f4*)&io[(size_t)row * DM_ + t * 4];
    float s  = x[0] + x[1] + x[2] + x[3];
    float s2 = x[0]*x[0] + x[1]*x[1] + x[2]*x[2] + x[3]*x[3];
#pragma unroll
    for (int o = 32; o > 0; o >>= 1) {
        s  += __shfl_down(s, o);
        s2 += __shfl_down(s2, o);
    }
    if ((t & 63) == 0) { wsum[t >> 6] = s; wsum2[t >> 6] = s2; }
    __syncthreads();
    s  = wsum[0]  + wsum[1]  + wsum[2]  + wsum[3];
    s2 = wsum2[0] + wsum2[1] + wsum2[2] + wsum2[3];
    const float m = s * (1.f / DM_);
    const float var = s2 * (1.f / DM_) - m * m;
    const float rstd = rsqrtf(var + 1e-5f);
    f4 g  = *(const f4*)&gamma[t * 4];
    f4 bb = *(const f4*)&beta[t * 4];
    f4 o = (x - m) * rstd * g + bb;
    *(f4*)&io[(size_t)row * DM_ + t * 4] = o;
}

// ---------------------------------------------------------------------------
// Workspace (226 MB):
//   [  0, 64) qp bf16
//   [ 64,128) kp bf16        | step1: aq [64,80) + wq_bf [80,82) | step8: wo_bf
//   [128,192) kvT bf16       | ak/av [128,144) + wk/wv [144,146) + omega_bf [146,147)
//   [192,208) vb bf16        | step1-2: qx bf16
//   [208,224) attnb bf16     | step3: kx bf16
//   [224,226) ksum f32
// ---------------------------------------------------------------------------
extern "C" void kernel_launch(void* const* d_in, const int* in_sizes, int n_in,
                              void* d_out, int out_size, void* d_ws, size_t ws_size,
                              hipStream_t stream) {
    const float* pre_q = (const float*)d_in[0];
    const float* pre_k = (const float*)d_in[1];
    const float* pre_v = (const float*)d_in[2];
    const float* wq    = (const float*)d_in[3];
    const float* wk    = (const float*)d_in[4];
    const float* wv    = (const float*)d_in[5];
    const float* wo    = (const float*)d_in[6];
    const float* gamma = (const float*)d_in[7];
    const float* beta  = (const float*)d_in[8];
    const float* omega = (const float*)d_in[9];
    const float* bvec  = (const float*)d_in[10];

    const size_t NEED = 226ull << 20;
    if (ws_size < NEED) return;

    char* w = (char*)d_ws;
    unsigned short* qp    = (unsigned short*)(w);
    unsigned short* kp    = (unsigned short*)(w + (64ull << 20));
    unsigned short* kvT   = (unsigned short*)(w + (128ull << 20));
    unsigned short* vb    = (unsigned short*)(w + (192ull << 20));
    unsigned short* attnb = (unsigned short*)(w + (208ull << 20));
    float*          ksum  = (float*)(w + (224ull << 20));
    unsigned short* aq    = (unsigned short*)(w + (64ull << 20));
    unsigned short* wq_bf = (unsigned short*)(w + (80ull << 20));
    unsigned short* qx    = vb;
    unsigned short* akv   = (unsigned short*)(w + (128ull << 20));
    unsigned short* wkv   = (unsigned short*)(w + (144ull << 20));
    unsigned short* om_bf = (unsigned short*)(w + (146ull << 20));
    unsigned short* kx    = attnb;
    unsigned short* wo_bf = (unsigned short*)(w + (64ull << 20));
    float*          outb  = (float*)d_out;

    const int n4_big = M_ * DM_ / 4;
    const int n4_w   = DM_ * DM_ / 4;
    const int n4_om  = R_ * D_ / 4;
    dim3 gg(DM_ / 128, M_ / 128);

    cvt_bf16<<<(n4_om + 255) / 256, 256, 0, stream>>>(omega, om_bf, n4_om);

    cvt_bf16<<<(n4_big + 255) / 256, 256, 0, stream>>>(pre_q, aq, n4_big);
    cvt_bf16<<<(n4_w + 255) / 256, 256, 0, stream>>>(wq, wq_bf, n4_w);
    gemm_mfma<<<gg, 256, 0, stream>>>(aq, wq_bf, nullptr, nullptr, qx, M_, DM_, DM_, 2);
    feat_mfma<<<M2_ / 64, 256, 0, stream>>>(qx, om_bf, bvec, qp);

    cvt_bf16<<<(n4_big + 255) / 256, 256, 0, stream>>>(pre_k, akv, n4_big);
    cvt_bf16<<<(n4_w + 255) / 256, 256, 0, stream>>>(wk, wkv, n4_w);
    gemm_mfma<<<gg, 256, 0, stream>>>(akv, wkv, nullptr, nullptr, kx, M_, DM_, DM_, 2);
    feat_mfma<<<M2_ / 64, 256, 0, stream>>>(kx, om_bf, bvec, kp);

    cvt_bf16<<<(n4_big + 255) / 256, 256, 0, stream>>>(pre_v, akv, n4_big);
    cvt_bf16<<<(n4_w + 255) / 256, 256, 0, stream>>>(wv, wkv, n4_w);
    gemm_mfma<<<gg, 256, 0, stream>>>(akv, wkv, nullptr, nullptr, vb, M_, DM_, DM_, 2);

    passA_mfma<<<dim3(NC_, H_, B_), 256, 0, stream>>>(kp, vb, kvT, ksum);
    passB_chain<<<dim3(64, H_, B_), 256, 0, stream>>>(kvT, ksum);
    passC_mfma<<<dim3(NC_, H_, B_), 256, 0, stream>>>(qp, kp, vb, kvT, ksum, attnb);

    cvt_bf16<<<(n4_w + 255) / 256, 256, 0, stream>>>(wo, wo_bf, n4_w);
    gemm_mfma<<<gg, 256, 0, stream>>>(attnb, wo_bf, pre_q, outb, nullptr, M_, DM_, DM_, 1);
    ln_kernel<<<M_, 256, 0, stream>>>(outb, gamma, beta);
}

// Round 7
// 388.695 us; speedup vs baseline: 1.0331x; 1.0331x over previous
//
#include <hip/hip_runtime.h>
#include <hip/hip_bf16.h>

// Performer (ORF linear attention) + out-proj + residual + LayerNorm.
// Round 7: passC Spref tile via async global_load_lds with pre-swizzled
// source (conflict-free ds_read_b128), prefetch overlapped with scores.

typedef float f4 __attribute__((ext_vector_type(4)));
typedef __attribute__((ext_vector_type(8))) short bf16x8;
typedef __attribute__((ext_vector_type(4))) float f32x4;
typedef unsigned short u16x4 __attribute__((ext_vector_type(4)));
typedef unsigned short u16x8 __attribute__((ext_vector_type(8)));

#define B_  4
#define L_  2048
#define H_  16
#define D_  64
#define DM_ 1024
#define R_  256
#define C_  64
#define NC_ (L_ / C_)
#define M_  (B_ * L_)
#define M2_ (M_ * H_)

static __device__ __forceinline__ unsigned short f2bu(float x) {
    __hip_bfloat16 h = __float2bfloat16(x);
    return *(unsigned short*)&h;
}
static __device__ __forceinline__ float bu2f(unsigned short u) {
    union { unsigned int i; float f; } c; c.i = ((unsigned int)u) << 16; return c.f;
}

typedef __attribute__((address_space(3))) void lds_void_t;
typedef __attribute__((address_space(1))) const void gvoid_t;
static __device__ __forceinline__ void gload16(const void* g, void* l) {
    __builtin_amdgcn_global_load_lds((gvoid_t*)g, (lds_void_t*)l, 16, 0, 0);
}

// ---------------------------------------------------------------------------
// fp32 -> bf16 cast, 4 elements/thread
// ---------------------------------------------------------------------------
__launch_bounds__(256)
__global__ void cvt_bf16(const float* __restrict__ in, unsigned short* __restrict__ out, int n4) {
    int i = blockIdx.x * 256 + threadIdx.x;
    if (i < n4) {
        f4 v = *(const f4*)&in[(size_t)i * 4];
        ushort4 o;
        o.x = f2bu(v[0]); o.y = f2bu(v[1]); o.z = f2bu(v[2]); o.w = f2bu(v[3]);
        *(ushort4*)&out[(size_t)i * 4] = o;
    }
}

// ---------------------------------------------------------------------------
// C[M,N] = A[M,K] @ B[N,K]^T, bf16 MFMA, 128x128 tile.
// mode 0: fp32 out; mode 1: fp32 out + fp32 resid; mode 2: bf16 out.
// ---------------------------------------------------------------------------
__launch_bounds__(256)
__global__ void gemm_mfma(const unsigned short* __restrict__ A,
                          const unsigned short* __restrict__ Bw,
                          const float* __restrict__ resid,
                          float* __restrict__ Cf, unsigned short* __restrict__ Cb,
                          int M, int N, int K, int mode) {
    __shared__ unsigned short Asl[128 * 32];
    __shared__ unsigned short Bsl[128 * 32];
    const int t = threadIdx.x;
    const int lane = t & 63, w = t >> 6;
    const int wr = w >> 1, wc = w & 1;
    const int row0 = blockIdx.y * 128, col0 = blockIdx.x * 128;
    const int sr0 = t >> 2, sk0 = (t & 3) * 8;
    const int lg = lane >> 4, lr = lane & 15;

    f32x4 acc[4][4] = {};
    for (int kk = 0; kk < K; kk += 32) {
        __syncthreads();
        gload16(&A [(size_t)(row0 + sr0)      * K + kk + sk0], &Asl[t * 8]);
        gload16(&A [(size_t)(row0 + sr0 + 64) * K + kk + sk0], &Asl[(t + 256) * 8]);
        gload16(&Bw[(size_t)(col0 + sr0)      * K + kk + sk0], &Bsl[t * 8]);
        gload16(&Bw[(size_t)(col0 + sr0 + 64) * K + kk + sk0], &Bsl[(t + 256) * 8]);
        __syncthreads();

        bf16x8 af[4], bfr[4];
#pragma unroll
        for (int m = 0; m < 4; ++m)
            af[m] = *(const bf16x8*)&Asl[(wr * 64 + m * 16 + lr) * 32 + lg * 8];
#pragma unroll
        for (int n = 0; n < 4; ++n)
            bfr[n] = *(const bf16x8*)&Bsl[(wc * 64 + n * 16 + lr) * 32 + lg * 8];
#pragma unroll
        for (int m = 0; m < 4; ++m)
#pragma unroll
            for (int n = 0; n < 4; ++n)
                acc[m][n] = __builtin_amdgcn_mfma_f32_16x16x32_bf16(af[m], bfr[n], acc[m][n], 0, 0, 0);
    }
#pragma unroll
    for (int m = 0; m < 4; ++m)
#pragma unroll
        for (int n = 0; n < 4; ++n) {
#pragma unroll
            for (int i = 0; i < 4; ++i) {
                int r  = row0 + wr * 64 + m * 16 + lg * 4 + i;
                int cc = col0 + wc * 64 + n * 16 + lr;
                size_t off = (size_t)r * N + cc;
                float v = acc[m][n][i];
                if (mode == 2) {
                    Cb[off] = f2bu(v);
                } else {
                    if (mode == 1) v += resid[off];
                    Cf[off] = v;
                }
            }
        }
}

// ---------------------------------------------------------------------------
// feat_mfma: out[m,r] = bf16( sqrt(2/R)*cos( dot(X[m,:64], omega[r,:64]) + b[r] ) )
// ---------------------------------------------------------------------------
__launch_bounds__(256)
__global__ void feat_mfma(const unsigned short* __restrict__ X,
                          const unsigned short* __restrict__ om,
                          const float* __restrict__ bvec,
                          unsigned short* __restrict__ out) {
    __shared__ unsigned short Xs[2 * 64 * 32];    // 8 KB
    __shared__ unsigned short Os[2 * 256 * 32];   // 32 KB
    __shared__ unsigned short Rs[64][264];        // 33 KB repack
    const int t = threadIdx.x;
    const int lane = t & 63, w = t >> 6;
    const int lg = lane >> 4, lr = lane & 15;
    const int m0 = blockIdx.x * 64;

#pragma unroll
    for (int i = 0; i < 2; ++i) {
        int cch = i * 256 + t;
        int ks = cch >> 8, row = (cch >> 2) & 63, sub = cch & 3;
        gload16(&X[(size_t)(m0 + row) * 64 + ks * 32 + sub * 8], &Xs[cch * 8]);
    }
#pragma unroll
    for (int i = 0; i < 8; ++i) {
        int cch = i * 256 + t;
        int ks = cch >> 10, r = (cch >> 2) & 255, sub = cch & 3;
        gload16(&om[(size_t)r * 64 + ks * 32 + sub * 8], &Os[cch * 8]);
    }
    __syncthreads();

    f32x4 acc[4][4] = {};
#pragma unroll
    for (int ks = 0; ks < 2; ++ks) {
        bf16x8 af[4], bfr[4];
#pragma unroll
        for (int m = 0; m < 4; ++m)
            af[m] = *(const bf16x8*)&Xs[ks * 2048 + (m * 16 + lr) * 32 + lg * 8];
#pragma unroll
        for (int n = 0; n < 4; ++n)
            bfr[n] = *(const bf16x8*)&Os[ks * 8192 + (w * 64 + n * 16 + lr) * 32 + lg * 8];
#pragma unroll
        for (int m = 0; m < 4; ++m)
#pragma unroll
            for (int n = 0; n < 4; ++n)
                acc[m][n] = __builtin_amdgcn_mfma_f32_16x16x32_bf16(af[m], bfr[n], acc[m][n], 0, 0, 0);
    }

    const float scale = 0.08838834764831845f;  // sqrt(2/256)
#pragma unroll
    for (int n = 0; n < 4; ++n) {
        const int col = w * 64 + n * 16 + lr;
        const float bb = bvec[col];
#pragma unroll
        for (int m = 0; m < 4; ++m)
#pragma unroll
            for (int ii = 0; ii < 4; ++ii)
                Rs[m * 16 + lg * 4 + ii][col] = f2bu(scale * __cosf(acc[m][n][ii] + bb));
    }
    __syncthreads();
#pragma unroll
    for (int i = 0; i < 8; ++i) {
        int cch = i * 256 + t;
        int row = cch >> 5, colc = (cch & 31) * 8;
        u16x8 vv = *(const u16x8*)&Rs[row][colc];
        *(u16x8*)&out[(size_t)(m0 + row) * 256 + colc] = vv;
    }
}

// ---------------------------------------------------------------------------
// passA (MFMA): kvT[bh][c][d][r] = sum_l kp[l][r]*vb[l][d] (bf16), ksum[r].
// ---------------------------------------------------------------------------
__launch_bounds__(256)
__global__ void passA_mfma(const unsigned short* __restrict__ kp, const unsigned short* __restrict__ vb,
                           unsigned short* __restrict__ kvT, float* __restrict__ ksum) {
    __shared__ __align__(16) unsigned short KPt[256][72];  // [r][l]
    __shared__ __align__(16) unsigned short Vt[64][72];    // [d][l]
    const int c = blockIdx.x, h = blockIdx.y, bz = blockIdx.z;
    const int t = threadIdx.x;
    const int lane = t & 63, w = t >> 6;
    const int lg = lane >> 4, lr = lane & 15;
    const int l0 = c * C_;
    const int bh = bz * H_ + h;

    {   // stage KP^T
        const int l4 = (t & 15) * 4, rs = (t >> 4) * 16;
        u16x8 row[4][2];
#pragma unroll
        for (int i = 0; i < 4; ++i) {
            const unsigned short* src = &kp[((size_t)(bz * L_ + l0 + l4 + i) * H_ + h) * R_ + rs];
            row[i][0] = *(const u16x8*)src;
            row[i][1] = *(const u16x8*)(src + 8);
        }
#pragma unroll
        for (int q = 0; q < 16; ++q) {
            u16x4 pk = { row[0][q >> 3][q & 7], row[1][q >> 3][q & 7],
                         row[2][q >> 3][q & 7], row[3][q >> 3][q & 7] };
            *(u16x4*)&KPt[rs + q][l4] = pk;
        }
    }
    {   // stage V^T (bf16 pass-through)
        const int d4 = (t & 15) * 4, ls = (t >> 4) * 4;
        u16x4 x[4];
#pragma unroll
        for (int i = 0; i < 4; ++i)
            x[i] = *(const u16x4*)&vb[(size_t)(bz * L_ + l0 + ls + i) * DM_ + h * 64 + d4];
#pragma unroll
        for (int q = 0; q < 4; ++q) {
            u16x4 pk = { x[0][q], x[1][q], x[2][q], x[3][q] };
            *(u16x4*)&Vt[d4 + q][ls] = pk;
        }
    }
    __syncthreads();

    f32x4 acc[4][4] = {};
#pragma unroll
    for (int ks = 0; ks < 2; ++ks) {
        bf16x8 af[4], bfr[4];
#pragma unroll
        for (int m = 0; m < 4; ++m)
            af[m] = *(const bf16x8*)&KPt[64 * w + 16 * m + lr][ks * 32 + lg * 8];
#pragma unroll
        for (int n = 0; n < 4; ++n)
            bfr[n] = *(const bf16x8*)&Vt[16 * n + lr][ks * 32 + lg * 8];
#pragma unroll
        for (int m = 0; m < 4; ++m)
#pragma unroll
            for (int n = 0; n < 4; ++n)
                acc[m][n] = __builtin_amdgcn_mfma_f32_16x16x32_bf16(af[m], bfr[n], acc[m][n], 0, 0, 0);
    }
    size_t sbase = ((size_t)(bh * NC_ + c)) * 64 * R_;
#pragma unroll
    for (int n = 0; n < 4; ++n)
#pragma unroll
        for (int m = 0; m < 4; ++m) {
            int d = 16 * n + lr;
            int r = 64 * w + 16 * m + lg * 4;
            u16x4 pk = { f2bu(acc[m][n][0]), f2bu(acc[m][n][1]),
                         f2bu(acc[m][n][2]), f2bu(acc[m][n][3]) };
            *(u16x4*)&kvT[sbase + (size_t)d * R_ + r] = pk;
        }
    {
        float s = 0.f;
#pragma unroll
        for (int j = 0; j < 8; ++j) {
            u16x8 vv = *(const u16x8*)&KPt[t][j * 8];
#pragma unroll
            for (int q = 0; q < 8; ++q) s += bu2f(vv[q]);
        }
        ksum[((size_t)(bh * NC_ + c)) * R_ + t] = s;
    }
}

// ---------------------------------------------------------------------------
// passB: exclusive prefix over chunks of kvT ([bh][c][d][r]) and ksum.
// ---------------------------------------------------------------------------
__launch_bounds__(256)
__global__ void passB_chain(unsigned short* __restrict__ kvT, float* __restrict__ ksum) {
    const int d = blockIdx.x, h = blockIdx.y, bz = blockIdx.z;
    const int t = threadIdx.x;
    const int bh = bz * H_ + h;
    size_t base = ((size_t)bh * NC_ * 64 + d) * R_ + t;
    const size_t cstride = (size_t)64 * R_;
    float run = 0.f;
    for (int c = 0; c < NC_; ++c) {
        size_t idx = base + (size_t)c * cstride;
        float tmp = bu2f(kvT[idx]);
        kvT[idx] = f2bu(run);
        run += tmp;
    }
    if (d == 0) {
        float rz = 0.f;
        for (int c = 0; c < NC_; ++c) {
            size_t idx = ((size_t)bh * NC_ + c) * R_ + t;
            float tmp = ksum[idx];
            ksum[idx] = rz;
            rz += tmp;
        }
    }
}

// ---------------------------------------------------------------------------
// passC (MFMA):
//   prologue: async gload_lds of the 32KB Spref tile (pre-swizzled source:
//             16B-slot s stored at s^(row&7)) — overlaps the scores phase.
//   scores:   A = mask(QP@KP^T) -> As LDS (kp streamed from global).
//   Spref:    oacc += QP @ Spref (B-frags from LDS, conflict-free reads);
//             dacc += QP @ zpref-broadcast-frag (den part 1).
//   AV:       oacc += A@V, racc = A@ones (den part 2), from LDS.
//   out = (oacc) / (max(den,1e-6)+1e-6), bf16.
// ---------------------------------------------------------------------------
__launch_bounds__(256)
__global__ void passC_mfma(const unsigned short* __restrict__ qp, const unsigned short* __restrict__ kp,
                           const unsigned short* __restrict__ vb, const unsigned short* __restrict__ kvT,
                           const float* __restrict__ zpref, unsigned short* __restrict__ attnb) {
    __shared__ __align__(16) unsigned short Sl[64 * 256];  // 32 KB, swizzled kvT tile
    __shared__ __align__(16) unsigned short Vt[80][72];    // [d][l], row64=ones (65..79 unread cols only)
    __shared__ __align__(16) unsigned short As[64][72];    // masked scores

    const int c = blockIdx.x, h = blockIdx.y, bz = blockIdx.z;
    const int t = threadIdx.x;
    const int lane = t & 63, w = t >> 6;
    const int lg = lane >> 4, lr = lane & 15;
    const int l0 = c * C_;
    const int bh = bz * H_ + h;
    const size_t sbase = ((size_t)(bh * NC_ + c)) * 64 * R_;
    const size_t zbase = ((size_t)(bh * NC_ + c)) * R_;

    // ---- async prefetch of Spref tile, swizzled source ----
    // LDS 16B-slot idx: row = idx>>5, s = idx&31; source slot = s ^ (row&7).
#pragma unroll
    for (int i = 0; i < 8; ++i) {
        int idx = i * 256 + t;
        int row = idx >> 5, s = idx & 31;
        gload16(&kvT[sbase + (size_t)row * R_ + ((s ^ (row & 7)) << 3)], &Sl[idx * 8]);
    }

    {   // stage V^T (bf16 pass-through)
        const int d4 = (t & 15) * 4, ls = (t >> 4) * 4;
        u16x4 x[4];
#pragma unroll
        for (int i = 0; i < 4; ++i)
            x[i] = *(const u16x4*)&vb[(size_t)(bz * L_ + l0 + ls + i) * DM_ + h * 64 + d4];
#pragma unroll
        for (int q = 0; q < 4; ++q) {
            u16x4 pk = { x[0][q], x[1][q], x[2][q], x[3][q] };
            *(u16x4*)&Vt[d4 + q][ls] = pk;
        }
    }
    if (t < 16) {
        u16x4 ones = { 0x3F80, 0x3F80, 0x3F80, 0x3F80 };
        *(u16x4*)&Vt[64][t * 4] = ones;
    }

    // Q fragments in registers (reused by scores and Spref phases)
    const size_t qrow = ((size_t)(bz * L_ + l0 + 16 * w + lr) * H_ + h) * R_;
    bf16x8 aq[8];
#pragma unroll
    for (int ks = 0; ks < 8; ++ks) aq[ks] = *(const bf16x8*)&qp[qrow + ks * 32 + lg * 8];

    // ---- scores (kp streamed from global; Sl prefetch in flight) ----
    f32x4 sacc[4] = {};
#pragma unroll
    for (int ks = 0; ks < 8; ++ks) {
#pragma unroll
        for (int n = 0; n < 4; ++n) {
            bf16x8 bk = *(const bf16x8*)&kp[((size_t)(bz * L_ + l0 + 16 * n + lr) * H_ + h) * R_ + ks * 32 + lg * 8];
            sacc[n] = __builtin_amdgcn_mfma_f32_16x16x32_bf16(aq[ks], bk, sacc[n], 0, 0, 0);
        }
    }
#pragma unroll
    for (int n = 0; n < 4; ++n)
#pragma unroll
        for (int ii = 0; ii < 4; ++ii) {
            int i_loc = 16 * w + lg * 4 + ii;
            int j_loc = 16 * n + lr;
            As[i_loc][j_loc] = (j_loc <= i_loc) ? f2bu(sacc[n][ii]) : (unsigned short)0;
        }
    __syncthreads();   // drains Sl prefetch (vmcnt) + As/Vt writes

    // ---- Spref phase from LDS (swizzled reads, conflict-free) ----
    f32x4 oacc[4] = {};
    f32x4 dacc = {};
#pragma unroll
    for (int ks = 0; ks < 8; ++ks) {
#pragma unroll
        for (int n = 0; n < 4; ++n) {
            int row = 16 * n + lr;                    // row&7 == lr&7
            int slot = (ks * 4 + lg) ^ (lr & 7);
            bf16x8 bs = *(const bf16x8*)&Sl[row * 256 + slot * 8];
            oacc[n] = __builtin_amdgcn_mfma_f32_16x16x32_bf16(aq[ks], bs, oacc[n], 0, 0, 0);
        }
        f4 z0 = *(const f4*)&zpref[zbase + ks * 32 + lg * 8];
        f4 z1 = *(const f4*)&zpref[zbase + ks * 32 + lg * 8 + 4];
        u16x8 zu = { f2bu(z0[0]), f2bu(z0[1]), f2bu(z0[2]), f2bu(z0[3]),
                     f2bu(z1[0]), f2bu(z1[1]), f2bu(z1[2]), f2bu(z1[3]) };
        dacc = __builtin_amdgcn_mfma_f32_16x16x32_bf16(aq[ks], *(bf16x8*)&zu, dacc, 0, 0, 0);
    }

    // ---- A@[V | ones] from LDS ----
    f32x4 racc = {};
#pragma unroll
    for (int ks = 0; ks < 2; ++ks) {
        bf16x8 aa = *(const bf16x8*)&As[16 * w + lr][ks * 32 + lg * 8];
#pragma unroll
        for (int n = 0; n < 4; ++n) {
            bf16x8 bv = *(const bf16x8*)&Vt[16 * n + lr][ks * 32 + lg * 8];
            oacc[n] = __builtin_amdgcn_mfma_f32_16x16x32_bf16(aa, bv, oacc[n], 0, 0, 0);
        }
        bf16x8 b4 = *(const bf16x8*)&Vt[64 + lr][ks * 32 + lg * 8];
        racc = __builtin_amdgcn_mfma_f32_16x16x32_bf16(aa, b4, racc, 0, 0, 0);
    }

    // ---- epilogue ----
#pragma unroll
    for (int ii = 0; ii < 4; ++ii) {
        float rs_ = __shfl(racc[ii], lane & 48, 64);   // lr==0 lane holds rowsum
        float den = rs_ + dacc[ii];
        float inv = 1.f / (fmaxf(den, 1e-6f) + 1e-6f);
#pragma unroll
        for (int n = 0; n < 4; ++n)
            attnb[(size_t)(bz * L_ + l0 + 16 * w + lg * 4 + ii) * DM_ + h * 64 + 16 * n + lr] =
                f2bu(oacc[n][ii] * inv);
    }
}

// ---------------------------------------------------------------------------
// In-place row LayerNorm over last dim (1024), eps=1e-5.
// ---------------------------------------------------------------------------
__launch_bounds__(256)
__global__ void ln_kernel(float* __restrict__ io, const float* __restrict__ gamma,
                          const float* __restrict__ beta) {
    __shared__ float wsum[4], wsum2[4];
    const int row = blockIdx.x;
    const int t = threadIdx.x;
    f4 x = *(const f4*)&io[(size_t)row * DM_ + t * 4];
    float s  = x[0] + x[1] + x[2] + x[3];
    float s2 = x[0]*x[0] + x[1]*x[1] + x[2]*x[2] + x[3]*x[3];
#pragma unroll
    for (int o = 32; o > 0; o >>= 1) {
        s  += __shfl_down(s, o);
        s2 += __shfl_down(s2, o);
    }
    if ((t & 63) == 0) { wsum[t >> 6] = s; wsum2[t >> 6] = s2; }
    __syncthreads();
    s  = wsum[0]  + wsum[1]  + wsum[2]  + wsum[3];
    s2 = wsum2[0] + wsum2[1] + wsum2[2] + wsum2[3];
    const float m = s * (1.f / DM_);
    const float var = s2 * (1.f / DM_) - m * m;
    const float rstd = rsqrtf(var + 1e-5f);
    f4 g  = *(const f4*)&gamma[t * 4];
    f4 bb = *(const f4*)&beta[t * 4];
    f4 o = (x - m) * rstd * g + bb;
    *(f4*)&io[(size_t)row * DM_ + t * 4] = o;
}

// ---------------------------------------------------------------------------
// Workspace (226 MB):
//   [  0, 64) qp bf16
//   [ 64,128) kp bf16        | step1: aq [64,80) + wq_bf [80,82) | step8: wo_bf
//   [128,192) kvT bf16       | ak/av [128,144) + wk/wv [144,146) + omega_bf [146,147)
//   [192,208) vb bf16        | step1-2: qx bf16
//   [208,224) attnb bf16     | step3: kx bf16
//   [224,226) ksum f32
// ---------------------------------------------------------------------------
extern "C" void kernel_launch(void* const* d_in, const int* in_sizes, int n_in,
                              void* d_out, int out_size, void* d_ws, size_t ws_size,
                              hipStream_t stream) {
    const float* pre_q = (const float*)d_in[0];
    const float* pre_k = (const float*)d_in[1];
    const float* pre_v = (const float*)d_in[2];
    const float* wq    = (const float*)d_in[3];
    const float* wk    = (const float*)d_in[4];
    const float* wv    = (const float*)d_in[5];
    const float* wo    = (const float*)d_in[6];
    const float* gamma = (const float*)d_in[7];
    const float* beta  = (const float*)d_in[8];
    const float* omega = (const float*)d_in[9];
    const float* bvec  = (const float*)d_in[10];

    const size_t NEED = 226ull << 20;
    if (ws_size < NEED) return;

    char* w = (char*)d_ws;
    unsigned short* qp    = (unsigned short*)(w);
    unsigned short* kp    = (unsigned short*)(w + (64ull << 20));
    unsigned short* kvT   = (unsigned short*)(w + (128ull << 20));
    unsigned short* vb    = (unsigned short*)(w + (192ull << 20));
    unsigned short* attnb = (unsigned short*)(w + (208ull << 20));
    float*          ksum  = (float*)(w + (224ull << 20));
    unsigned short* aq    = (unsigned short*)(w + (64ull << 20));
    unsigned short* wq_bf = (unsigned short*)(w + (80ull << 20));
    unsigned short* qx    = vb;
    unsigned short* akv   = (unsigned short*)(w + (128ull << 20));
    unsigned short* wkv   = (unsigned short*)(w + (144ull << 20));
    unsigned short* om_bf = (unsigned short*)(w + (146ull << 20));
    unsigned short* kx    = attnb;
    unsigned short* wo_bf = (unsigned short*)(w + (64ull << 20));
    float*          outb  = (float*)d_out;

    const int n4_big = M_ * DM_ / 4;
    const int n4_w   = DM_ * DM_ / 4;
    const int n4_om  = R_ * D_ / 4;
    dim3 gg(DM_ / 128, M_ / 128);

    cvt_bf16<<<(n4_om + 255) / 256, 256, 0, stream>>>(omega, om_bf, n4_om);

    cvt_bf16<<<(n4_big + 255) / 256, 256, 0, stream>>>(pre_q, aq, n4_big);
    cvt_bf16<<<(n4_w + 255) / 256, 256, 0, stream>>>(wq, wq_bf, n4_w);
    gemm_mfma<<<gg, 256, 0, stream>>>(aq, wq_bf, nullptr, nullptr, qx, M_, DM_, DM_, 2);
    feat_mfma<<<M2_ / 64, 256, 0, stream>>>(qx, om_bf, bvec, qp);

    cvt_bf16<<<(n4_big + 255) / 256, 256, 0, stream>>>(pre_k, akv, n4_big);
    cvt_bf16<<<(n4_w + 255) / 256, 256, 0, stream>>>(wk, wkv, n4_w);
    gemm_mfma<<<gg, 256, 0, stream>>>(akv, wkv, nullptr, nullptr, kx, M_, DM_, DM_, 2);
    feat_mfma<<<M2_ / 64, 256, 0, stream>>>(kx, om_bf, bvec, kp);

    cvt_bf16<<<(n4_big + 255) / 256, 256, 0, stream>>>(pre_v, akv, n4_big);
    cvt_bf16<<<(n4_w + 255) / 256, 256, 0, stream>>>(wv, wkv, n4_w);
    gemm_mfma<<<gg, 256, 0, stream>>>(akv, wkv, nullptr, nullptr, vb, M_, DM_, DM_, 2);

    passA_mfma<<<dim3(NC_, H_, B_), 256, 0, stream>>>(kp, vb, kvT, ksum);
    passB_chain<<<dim3(64, H_, B_), 256, 0, stream>>>(kvT, ksum);
    passC_mfma<<<dim3(NC_, H_, B_), 256, 0, stream>>>(qp, kp, vb, kvT, ksum, attnb);

    cvt_bf16<<<(n4_w + 255) / 256, 256, 0, stream>>>(wo, wo_bf, n4_w);
    gemm_mfma<<<gg, 256, 0, stream>>>(attnb, wo_bf, pre_q, outb, nullptr, M_, DM_, DM_, 1);
    ln_kernel<<<M_, 256, 0, stream>>>(outb, gamma, beta);
}

// Round 8
// 369.736 us; speedup vs baseline: 1.0861x; 1.0513x over previous
//
#include <hip/hip_runtime.h>
#include <hip/hip_bf16.h>

// Performer (ORF linear attention) + out-proj + residual + LayerNorm.
// Round 8: passC scores-phase register hoisting (2x16-fragment batches),
// zpref fragment hoist, setprio around MFMA; gemm XCD-chunked swizzle.

typedef float f4 __attribute__((ext_vector_type(4)));
typedef __attribute__((ext_vector_type(8))) short bf16x8;
typedef __attribute__((ext_vector_type(4))) float f32x4;
typedef unsigned short u16x4 __attribute__((ext_vector_type(4)));
typedef unsigned short u16x8 __attribute__((ext_vector_type(8)));

#define B_  4
#define L_  2048
#define H_  16
#define D_  64
#define DM_ 1024
#define R_  256
#define C_  64
#define NC_ (L_ / C_)
#define M_  (B_ * L_)
#define M2_ (M_ * H_)

static __device__ __forceinline__ unsigned short f2bu(float x) {
    __hip_bfloat16 h = __float2bfloat16(x);
    return *(unsigned short*)&h;
}
static __device__ __forceinline__ float bu2f(unsigned short u) {
    union { unsigned int i; float f; } c; c.i = ((unsigned int)u) << 16; return c.f;
}

typedef __attribute__((address_space(3))) void lds_void_t;
typedef __attribute__((address_space(1))) const void gvoid_t;
static __device__ __forceinline__ void gload16(const void* g, void* l) {
    __builtin_amdgcn_global_load_lds((gvoid_t*)g, (lds_void_t*)l, 16, 0, 0);
}

// ---------------------------------------------------------------------------
// fp32 -> bf16 cast, 4 elements/thread
// ---------------------------------------------------------------------------
__launch_bounds__(256)
__global__ void cvt_bf16(const float* __restrict__ in, unsigned short* __restrict__ out, int n4) {
    int i = blockIdx.x * 256 + threadIdx.x;
    if (i < n4) {
        f4 v = *(const f4*)&in[(size_t)i * 4];
        ushort4 o;
        o.x = f2bu(v[0]); o.y = f2bu(v[1]); o.z = f2bu(v[2]); o.w = f2bu(v[3]);
        *(ushort4*)&out[(size_t)i * 4] = o;
    }
}

// ---------------------------------------------------------------------------
// C[M,N] = A[M,K] @ B[N,K]^T, bf16 MFMA, 128x128 tile, XCD-chunked swizzle.
// mode 0: fp32 out; mode 1: fp32 out + fp32 resid; mode 2: bf16 out.
// ---------------------------------------------------------------------------
__launch_bounds__(256)
__global__ void gemm_mfma(const unsigned short* __restrict__ A,
                          const unsigned short* __restrict__ Bw,
                          const float* __restrict__ resid,
                          float* __restrict__ Cf, unsigned short* __restrict__ Cb,
                          int M, int N, int K, int mode) {
    __shared__ unsigned short Asl[128 * 32];
    __shared__ unsigned short Bsl[128 * 32];
    const int t = threadIdx.x;
    const int lane = t & 63, w = t >> 6;
    const int wr = w >> 1, wc = w & 1;
    // XCD-chunked bijective swizzle (nwg multiple of 8)
    const int nwg = gridDim.x * gridDim.y;
    const int bid = blockIdx.y * gridDim.x + blockIdx.x;
    const int cpx = nwg >> 3;
    const int swz = (bid & 7) * cpx + (bid >> 3);
    const int row0 = (swz / gridDim.x) * 128, col0 = (swz % gridDim.x) * 128;
    const int sr0 = t >> 2, sk0 = (t & 3) * 8;
    const int lg = lane >> 4, lr = lane & 15;

    f32x4 acc[4][4] = {};
    for (int kk = 0; kk < K; kk += 32) {
        __syncthreads();
        gload16(&A [(size_t)(row0 + sr0)      * K + kk + sk0], &Asl[t * 8]);
        gload16(&A [(size_t)(row0 + sr0 + 64) * K + kk + sk0], &Asl[(t + 256) * 8]);
        gload16(&Bw[(size_t)(col0 + sr0)      * K + kk + sk0], &Bsl[t * 8]);
        gload16(&Bw[(size_t)(col0 + sr0 + 64) * K + kk + sk0], &Bsl[(t + 256) * 8]);
        __syncthreads();

        bf16x8 af[4], bfr[4];
#pragma unroll
        for (int m = 0; m < 4; ++m)
            af[m] = *(const bf16x8*)&Asl[(wr * 64 + m * 16 + lr) * 32 + lg * 8];
#pragma unroll
        for (int n = 0; n < 4; ++n)
            bfr[n] = *(const bf16x8*)&Bsl[(wc * 64 + n * 16 + lr) * 32 + lg * 8];
#pragma unroll
        for (int m = 0; m < 4; ++m)
#pragma unroll
            for (int n = 0; n < 4; ++n)
                acc[m][n] = __builtin_amdgcn_mfma_f32_16x16x32_bf16(af[m], bfr[n], acc[m][n], 0, 0, 0);
    }
#pragma unroll
    for (int m = 0; m < 4; ++m)
#pragma unroll
        for (int n = 0; n < 4; ++n) {
#pragma unroll
            for (int i = 0; i < 4; ++i) {
                int r  = row0 + wr * 64 + m * 16 + lg * 4 + i;
                int cc = col0 + wc * 64 + n * 16 + lr;
                size_t off = (size_t)r * N + cc;
                float v = acc[m][n][i];
                if (mode == 2) {
                    Cb[off] = f2bu(v);
                } else {
                    if (mode == 1) v += resid[off];
                    Cf[off] = v;
                }
            }
        }
}

// ---------------------------------------------------------------------------
// feat_mfma: out[m,r] = bf16( sqrt(2/R)*cos( dot(X[m,:64], omega[r,:64]) + b[r] ) )
// ---------------------------------------------------------------------------
__launch_bounds__(256)
__global__ void feat_mfma(const unsigned short* __restrict__ X,
                          const unsigned short* __restrict__ om,
                          const float* __restrict__ bvec,
                          unsigned short* __restrict__ out) {
    __shared__ unsigned short Xs[2 * 64 * 32];    // 8 KB
    __shared__ unsigned short Os[2 * 256 * 32];   // 32 KB
    __shared__ unsigned short Rs[64][264];        // 33 KB repack
    const int t = threadIdx.x;
    const int lane = t & 63, w = t >> 6;
    const int lg = lane >> 4, lr = lane & 15;
    const int m0 = blockIdx.x * 64;

#pragma unroll
    for (int i = 0; i < 2; ++i) {
        int cch = i * 256 + t;
        int ks = cch >> 8, row = (cch >> 2) & 63, sub = cch & 3;
        gload16(&X[(size_t)(m0 + row) * 64 + ks * 32 + sub * 8], &Xs[cch * 8]);
    }
#pragma unroll
    for (int i = 0; i < 8; ++i) {
        int cch = i * 256 + t;
        int ks = cch >> 10, r = (cch >> 2) & 255, sub = cch & 3;
        gload16(&om[(size_t)r * 64 + ks * 32 + sub * 8], &Os[cch * 8]);
    }
    __syncthreads();

    f32x4 acc[4][4] = {};
#pragma unroll
    for (int ks = 0; ks < 2; ++ks) {
        bf16x8 af[4], bfr[4];
#pragma unroll
        for (int m = 0; m < 4; ++m)
            af[m] = *(const bf16x8*)&Xs[ks * 2048 + (m * 16 + lr) * 32 + lg * 8];
#pragma unroll
        for (int n = 0; n < 4; ++n)
            bfr[n] = *(const bf16x8*)&Os[ks * 8192 + (w * 64 + n * 16 + lr) * 32 + lg * 8];
#pragma unroll
        for (int m = 0; m < 4; ++m)
#pragma unroll
            for (int n = 0; n < 4; ++n)
                acc[m][n] = __builtin_amdgcn_mfma_f32_16x16x32_bf16(af[m], bfr[n], acc[m][n], 0, 0, 0);
    }

    const float scale = 0.08838834764831845f;  // sqrt(2/256)
#pragma unroll
    for (int n = 0; n < 4; ++n) {
        const int col = w * 64 + n * 16 + lr;
        const float bb = bvec[col];
#pragma unroll
        for (int m = 0; m < 4; ++m)
#pragma unroll
            for (int ii = 0; ii < 4; ++ii)
                Rs[m * 16 + lg * 4 + ii][col] = f2bu(scale * __cosf(acc[m][n][ii] + bb));
    }
    __syncthreads();
#pragma unroll
    for (int i = 0; i < 8; ++i) {
        int cch = i * 256 + t;
        int row = cch >> 5, colc = (cch & 31) * 8;
        u16x8 vv = *(const u16x8*)&Rs[row][colc];
        *(u16x8*)&out[(size_t)(m0 + row) * 256 + colc] = vv;
    }
}

// ---------------------------------------------------------------------------
// passA (MFMA): kvT[bh][c][d][r] = sum_l kp[l][r]*vb[l][d] (bf16), ksum[r].
// ---------------------------------------------------------------------------
__launch_bounds__(256)
__global__ void passA_mfma(const unsigned short* __restrict__ kp, const unsigned short* __restrict__ vb,
                           unsigned short* __restrict__ kvT, float* __restrict__ ksum) {
    __shared__ __align__(16) unsigned short KPt[256][72];  // [r][l]
    __shared__ __align__(16) unsigned short Vt[64][72];    // [d][l]
    const int c = blockIdx.x, h = blockIdx.y, bz = blockIdx.z;
    const int t = threadIdx.x;
    const int lane = t & 63, w = t >> 6;
    const int lg = lane >> 4, lr = lane & 15;
    const int l0 = c * C_;
    const int bh = bz * H_ + h;

    {   // stage KP^T
        const int l4 = (t & 15) * 4, rs = (t >> 4) * 16;
        u16x8 row[4][2];
#pragma unroll
        for (int i = 0; i < 4; ++i) {
            const unsigned short* src = &kp[((size_t)(bz * L_ + l0 + l4 + i) * H_ + h) * R_ + rs];
            row[i][0] = *(const u16x8*)src;
            row[i][1] = *(const u16x8*)(src + 8);
        }
#pragma unroll
        for (int q = 0; q < 16; ++q) {
            u16x4 pk = { row[0][q >> 3][q & 7], row[1][q >> 3][q & 7],
                         row[2][q >> 3][q & 7], row[3][q >> 3][q & 7] };
            *(u16x4*)&KPt[rs + q][l4] = pk;
        }
    }
    {   // stage V^T (bf16 pass-through)
        const int d4 = (t & 15) * 4, ls = (t >> 4) * 4;
        u16x4 x[4];
#pragma unroll
        for (int i = 0; i < 4; ++i)
            x[i] = *(const u16x4*)&vb[(size_t)(bz * L_ + l0 + ls + i) * DM_ + h * 64 + d4];
#pragma unroll
        for (int q = 0; q < 4; ++q) {
            u16x4 pk = { x[0][q], x[1][q], x[2][q], x[3][q] };
            *(u16x4*)&Vt[d4 + q][ls] = pk;
        }
    }
    __syncthreads();

    f32x4 acc[4][4] = {};
#pragma unroll
    for (int ks = 0; ks < 2; ++ks) {
        bf16x8 af[4], bfr[4];
#pragma unroll
        for (int m = 0; m < 4; ++m)
            af[m] = *(const bf16x8*)&KPt[64 * w + 16 * m + lr][ks * 32 + lg * 8];
#pragma unroll
        for (int n = 0; n < 4; ++n)
            bfr[n] = *(const bf16x8*)&Vt[16 * n + lr][ks * 32 + lg * 8];
#pragma unroll
        for (int m = 0; m < 4; ++m)
#pragma unroll
            for (int n = 0; n < 4; ++n)
                acc[m][n] = __builtin_amdgcn_mfma_f32_16x16x32_bf16(af[m], bfr[n], acc[m][n], 0, 0, 0);
    }
    size_t sbase = ((size_t)(bh * NC_ + c)) * 64 * R_;
#pragma unroll
    for (int n = 0; n < 4; ++n)
#pragma unroll
        for (int m = 0; m < 4; ++m) {
            int d = 16 * n + lr;
            int r = 64 * w + 16 * m + lg * 4;
            u16x4 pk = { f2bu(acc[m][n][0]), f2bu(acc[m][n][1]),
                         f2bu(acc[m][n][2]), f2bu(acc[m][n][3]) };
            *(u16x4*)&kvT[sbase + (size_t)d * R_ + r] = pk;
        }
    {
        float s = 0.f;
#pragma unroll
        for (int j = 0; j < 8; ++j) {
            u16x8 vv = *(const u16x8*)&KPt[t][j * 8];
#pragma unroll
            for (int q = 0; q < 8; ++q) s += bu2f(vv[q]);
        }
        ksum[((size_t)(bh * NC_ + c)) * R_ + t] = s;
    }
}

// ---------------------------------------------------------------------------
// passB: exclusive prefix over chunks of kvT ([bh][c][d][r]) and ksum.
// ---------------------------------------------------------------------------
__launch_bounds__(256)
__global__ void passB_chain(unsigned short* __restrict__ kvT, float* __restrict__ ksum) {
    const int d = blockIdx.x, h = blockIdx.y, bz = blockIdx.z;
    const int t = threadIdx.x;
    const int bh = bz * H_ + h;
    size_t base = ((size_t)bh * NC_ * 64 + d) * R_ + t;
    const size_t cstride = (size_t)64 * R_;
    float run = 0.f;
    for (int c = 0; c < NC_; ++c) {
        size_t idx = base + (size_t)c * cstride;
        float tmp = bu2f(kvT[idx]);
        kvT[idx] = f2bu(run);
        run += tmp;
    }
    if (d == 0) {
        float rz = 0.f;
        for (int c = 0; c < NC_; ++c) {
            size_t idx = ((size_t)bh * NC_ + c) * R_ + t;
            float tmp = ksum[idx];
            ksum[idx] = rz;
            rz += tmp;
        }
    }
}

// ---------------------------------------------------------------------------
// passC (MFMA):
//   prologue: async gload_lds of 32KB Spref tile (pre-swizzled source).
//   scores:   A = mask(QP@KP^T), bk fragments REGISTER-HOISTED 16 at a time.
//   Spref:    oacc += QP@Spref (LDS swizzled), dacc += QP@zu (zu hoisted).
//   AV:       oacc += A@V, racc = A@ones.
//   out = oacc / (max(den,1e-6)+1e-6), bf16.
// ---------------------------------------------------------------------------
__launch_bounds__(256)
__global__ void passC_mfma(const unsigned short* __restrict__ qp, const unsigned short* __restrict__ kp,
                           const unsigned short* __restrict__ vb, const unsigned short* __restrict__ kvT,
                           const float* __restrict__ zpref, unsigned short* __restrict__ attnb) {
    __shared__ __align__(16) unsigned short Sl[64 * 256];  // 32 KB, swizzled kvT tile
    __shared__ __align__(16) unsigned short Vt[80][72];    // [d][l], row64=ones
    __shared__ __align__(16) unsigned short As[64][72];    // masked scores

    const int c = blockIdx.x, h = blockIdx.y, bz = blockIdx.z;
    const int t = threadIdx.x;
    const int lane = t & 63, w = t >> 6;
    const int lg = lane >> 4, lr = lane & 15;
    const int l0 = c * C_;
    const int bh = bz * H_ + h;
    const size_t sbase = ((size_t)(bh * NC_ + c)) * 64 * R_;
    const size_t zbase = ((size_t)(bh * NC_ + c)) * R_;

    // ---- async prefetch of Spref tile, swizzled source ----
#pragma unroll
    for (int i = 0; i < 8; ++i) {
        int idx = i * 256 + t;
        int row = idx >> 5, s = idx & 31;
        gload16(&kvT[sbase + (size_t)row * R_ + ((s ^ (row & 7)) << 3)], &Sl[idx * 8]);
    }

    {   // stage V^T (bf16 pass-through)
        const int d4 = (t & 15) * 4, ls = (t >> 4) * 4;
        u16x4 x[4];
#pragma unroll
        for (int i = 0; i < 4; ++i)
            x[i] = *(const u16x4*)&vb[(size_t)(bz * L_ + l0 + ls + i) * DM_ + h * 64 + d4];
#pragma unroll
        for (int q = 0; q < 4; ++q) {
            u16x4 pk = { x[0][q], x[1][q], x[2][q], x[3][q] };
            *(u16x4*)&Vt[d4 + q][ls] = pk;
        }
    }
    if (t < 16) {
        u16x4 ones = { 0x3F80, 0x3F80, 0x3F80, 0x3F80 };
        *(u16x4*)&Vt[64][t * 4] = ones;
    }

    // Q fragments in registers (reused by scores and Spref phases)
    const size_t qrow = ((size_t)(bz * L_ + l0 + 16 * w + lr) * H_ + h) * R_;
    bf16x8 aq[8];
#pragma unroll
    for (int ks = 0; ks < 8; ++ks) aq[ks] = *(const bf16x8*)&qp[qrow + ks * 32 + lg * 8];

    // ---- scores: two half-hoists of 16 bk fragments each ----
    f32x4 sacc[4] = {};
#pragma unroll
    for (int half = 0; half < 2; ++half) {
        bf16x8 bk[4][4];
#pragma unroll
        for (int k2 = 0; k2 < 4; ++k2)
#pragma unroll
            for (int n = 0; n < 4; ++n)
                bk[k2][n] = *(const bf16x8*)&kp[((size_t)(bz * L_ + l0 + 16 * n + lr) * H_ + h) * R_
                                                + (half * 4 + k2) * 32 + lg * 8];
        __builtin_amdgcn_s_setprio(1);
#pragma unroll
        for (int k2 = 0; k2 < 4; ++k2)
#pragma unroll
            for (int n = 0; n < 4; ++n)
                sacc[n] = __builtin_amdgcn_mfma_f32_16x16x32_bf16(aq[half * 4 + k2], bk[k2][n], sacc[n], 0, 0, 0);
        __builtin_amdgcn_s_setprio(0);
    }
#pragma unroll
    for (int n = 0; n < 4; ++n)
#pragma unroll
        for (int ii = 0; ii < 4; ++ii) {
            int i_loc = 16 * w + lg * 4 + ii;
            int j_loc = 16 * n + lr;
            As[i_loc][j_loc] = (j_loc <= i_loc) ? f2bu(sacc[n][ii]) : (unsigned short)0;
        }

    // hoist zpref fragments (L2-resident)
    u16x8 zu[8];
#pragma unroll
    for (int ks = 0; ks < 8; ++ks) {
        f4 z0 = *(const f4*)&zpref[zbase + ks * 32 + lg * 8];
        f4 z1 = *(const f4*)&zpref[zbase + ks * 32 + lg * 8 + 4];
        zu[ks] = u16x8{ f2bu(z0[0]), f2bu(z0[1]), f2bu(z0[2]), f2bu(z0[3]),
                        f2bu(z1[0]), f2bu(z1[1]), f2bu(z1[2]), f2bu(z1[3]) };
    }
    __syncthreads();   // drains Sl prefetch (vmcnt) + As/Vt writes

    // ---- Spref phase from LDS (swizzled reads, conflict-free) ----
    f32x4 oacc[4] = {};
    f32x4 dacc = {};
    __builtin_amdgcn_s_setprio(1);
#pragma unroll
    for (int ks = 0; ks < 8; ++ks) {
#pragma unroll
        for (int n = 0; n < 4; ++n) {
            int row = 16 * n + lr;                    // row&7 == lr&7
            int slot = (ks * 4 + lg) ^ (lr & 7);
            bf16x8 bs = *(const bf16x8*)&Sl[row * 256 + slot * 8];
            oacc[n] = __builtin_amdgcn_mfma_f32_16x16x32_bf16(aq[ks], bs, oacc[n], 0, 0, 0);
        }
        dacc = __builtin_amdgcn_mfma_f32_16x16x32_bf16(aq[ks], *(bf16x8*)&zu[ks], dacc, 0, 0, 0);
    }

    // ---- A@[V | ones] from LDS ----
    f32x4 racc = {};
#pragma unroll
    for (int ks = 0; ks < 2; ++ks) {
        bf16x8 aa = *(const bf16x8*)&As[16 * w + lr][ks * 32 + lg * 8];
#pragma unroll
        for (int n = 0; n < 4; ++n) {
            bf16x8 bv = *(const bf16x8*)&Vt[16 * n + lr][ks * 32 + lg * 8];
            oacc[n] = __builtin_amdgcn_mfma_f32_16x16x32_bf16(aa, bv, oacc[n], 0, 0, 0);
        }
        bf16x8 b4 = *(const bf16x8*)&Vt[64 + lr][ks * 32 + lg * 8];
        racc = __builtin_amdgcn_mfma_f32_16x16x32_bf16(aa, b4, racc, 0, 0, 0);
    }
    __builtin_amdgcn_s_setprio(0);

    // ---- epilogue ----
#pragma unroll
    for (int ii = 0; ii < 4; ++ii) {
        float rs_ = __shfl(racc[ii], lane & 48, 64);   // lr==0 lane holds rowsum
        float den = rs_ + dacc[ii];
        float inv = 1.f / (fmaxf(den, 1e-6f) + 1e-6f);
#pragma unroll
        for (int n = 0; n < 4; ++n)
            attnb[(size_t)(bz * L_ + l0 + 16 * w + lg * 4 + ii) * DM_ + h * 64 + 16 * n + lr] =
                f2bu(oacc[n][ii] * inv);
    }
}

// ---------------------------------------------------------------------------
// In-place row LayerNorm over last dim (1024), eps=1e-5.
// ---------------------------------------------------------------------------
__launch_bounds__(256)
__global__ void ln_kernel(float* __restrict__ io, const float* __restrict__ gamma,
                          const float* __restrict__ beta) {
    __shared__ float wsum[4], wsum2[4];
    const int row = blockIdx.x;
    const int t = threadIdx.x;
    f4 x = *(const f4*)&io[(size_t)row * DM_ + t * 4];
    float s  = x[0] + x[1] + x[2] + x[3];
    float s2 = x[0]*x[0] + x[1]*x[1] + x[2]*x[2] + x[3]*x[3];
#pragma unroll
    for (int o = 32; o > 0; o >>= 1) {
        s  += __shfl_down(s, o);
        s2 += __shfl_down(s2, o);
    }
    if ((t & 63) == 0) { wsum[t >> 6] = s; wsum2[t >> 6] = s2; }
    __syncthreads();
    s  = wsum[0]  + wsum[1]  + wsum[2]  + wsum[3];
    s2 = wsum2[0] + wsum2[1] + wsum2[2] + wsum2[3];
    const float m = s * (1.f / DM_);
    const float var = s2 * (1.f / DM_) - m * m;
    const float rstd = rsqrtf(var + 1e-5f);
    f4 g  = *(const f4*)&gamma[t * 4];
    f4 bb = *(const f4*)&beta[t * 4];
    f4 o = (x - m) * rstd * g + bb;
    *(f4*)&io[(size_t)row * DM_ + t * 4] = o;
}

// ---------------------------------------------------------------------------
// Workspace (226 MB):
//   [  0, 64) qp bf16
//   [ 64,128) kp bf16        | step1: aq [64,80) + wq_bf [80,82) | step8: wo_bf
//   [128,192) kvT bf16       | ak/av [128,144) + wk/wv [144,146) + omega_bf [146,147)
//   [192,208) vb bf16        | step1-2: qx bf16
//   [208,224) attnb bf16     | step3: kx bf16
//   [224,226) ksum f32
// ---------------------------------------------------------------------------
extern "C" void kernel_launch(void* const* d_in, const int* in_sizes, int n_in,
                              void* d_out, int out_size, void* d_ws, size_t ws_size,
                              hipStream_t stream) {
    const float* pre_q = (const float*)d_in[0];
    const float* pre_k = (const float*)d_in[1];
    const float* pre_v = (const float*)d_in[2];
    const float* wq    = (const float*)d_in[3];
    const float* wk    = (const float*)d_in[4];
    const float* wv    = (const float*)d_in[5];
    const float* wo    = (const float*)d_in[6];
    const float* gamma = (const float*)d_in[7];
    const float* beta  = (const float*)d_in[8];
    const float* omega = (const float*)d_in[9];
    const float* bvec  = (const float*)d_in[10];

    const size_t NEED = 226ull << 20;
    if (ws_size < NEED) return;

    char* w = (char*)d_ws;
    unsigned short* qp    = (unsigned short*)(w);
    unsigned short* kp    = (unsigned short*)(w + (64ull << 20));
    unsigned short* kvT   = (unsigned short*)(w + (128ull << 20));
    unsigned short* vb    = (unsigned short*)(w + (192ull << 20));
    unsigned short* attnb = (unsigned short*)(w + (208ull << 20));
    float*          ksum  = (float*)(w + (224ull << 20));
    unsigned short* aq    = (unsigned short*)(w + (64ull << 20));
    unsigned short* wq_bf = (unsigned short*)(w + (80ull << 20));
    unsigned short* qx    = vb;
    unsigned short* akv   = (unsigned short*)(w + (128ull << 20));
    unsigned short* wkv   = (unsigned short*)(w + (144ull << 20));
    unsigned short* om_bf = (unsigned short*)(w + (146ull << 20));
    unsigned short* kx    = attnb;
    unsigned short* wo_bf = (unsigned short*)(w + (64ull << 20));
    float*          outb  = (float*)d_out;

    const int n4_big = M_ * DM_ / 4;
    const int n4_w   = DM_ * DM_ / 4;
    const int n4_om  = R_ * D_ / 4;
    dim3 gg(DM_ / 128, M_ / 128);

    cvt_bf16<<<(n4_om + 255) / 256, 256, 0, stream>>>(omega, om_bf, n4_om);

    cvt_bf16<<<(n4_big + 255) / 256, 256, 0, stream>>>(pre_q, aq, n4_big);
    cvt_bf16<<<(n4_w + 255) / 256, 256, 0, stream>>>(wq, wq_bf, n4_w);
    gemm_mfma<<<gg, 256, 0, stream>>>(aq, wq_bf, nullptr, nullptr, qx, M_, DM_, DM_, 2);
    feat_mfma<<<M2_ / 64, 256, 0, stream>>>(qx, om_bf, bvec, qp);

    cvt_bf16<<<(n4_big + 255) / 256, 256, 0, stream>>>(pre_k, akv, n4_big);
    cvt_bf16<<<(n4_w + 255) / 256, 256, 0, stream>>>(wk, wkv, n4_w);
    gemm_mfma<<<gg, 256, 0, stream>>>(akv, wkv, nullptr, nullptr, kx, M_, DM_, DM_, 2);
    feat_mfma<<<M2_ / 64, 256, 0, stream>>>(kx, om_bf, bvec, kp);

    cvt_bf16<<<(n4_big + 255) / 256, 256, 0, stream>>>(pre_v, akv, n4_big);
    cvt_bf16<<<(n4_w + 255) / 256, 256, 0, stream>>>(wv, wkv, n4_w);
    gemm_mfma<<<gg, 256, 0, stream>>>(akv, wkv, nullptr, nullptr, vb, M_, DM_, DM_, 2);

    passA_mfma<<<dim3(NC_, H_, B_), 256, 0, stream>>>(kp, vb, kvT, ksum);
    passB_chain<<<dim3(64, H_, B_), 256, 0, stream>>>(kvT, ksum);
    passC_mfma<<<dim3(NC_, H_, B_), 256, 0, stream>>>(qp, kp, vb, kvT, ksum, attnb);

    cvt_bf16<<<(n4_w + 255) / 256, 256, 0, stream>>>(wo, wo_bf, n4_w);
    gemm_mfma<<<gg, 256, 0, stream>>>(attnb, wo_bf, pre_q, outb, nullptr, M_, DM_, DM_, 1);
    ln_kernel<<<M_, 256, 0, stream>>>(outb, gamma, beta);
}

// Round 9
// 300.694 us; speedup vs baseline: 1.3355x; 1.2296x over previous
//
#include <hip/hip_runtime.h>
#include <hip/hip_bf16.h>

// Performer (ORF linear attention) + out-proj + residual + LayerNorm.
// Round 9: batch QKV projections (blockIdx.z), batch feature maps, batch
// input casts -> fixes grid-starved GEMM occupancy (2 -> 6 blocks/CU).

typedef float f4 __attribute__((ext_vector_type(4)));
typedef __attribute__((ext_vector_type(8))) short bf16x8;
typedef __attribute__((ext_vector_type(4))) float f32x4;
typedef unsigned short u16x4 __attribute__((ext_vector_type(4)));
typedef unsigned short u16x8 __attribute__((ext_vector_type(8)));

#define B_  4
#define L_  2048
#define H_  16
#define D_  64
#define DM_ 1024
#define R_  256
#define C_  64
#define NC_ (L_ / C_)
#define M_  (B_ * L_)
#define M2_ (M_ * H_)

static __device__ __forceinline__ unsigned short f2bu(float x) {
    __hip_bfloat16 h = __float2bfloat16(x);
    return *(unsigned short*)&h;
}
static __device__ __forceinline__ float bu2f(unsigned short u) {
    union { unsigned int i; float f; } c; c.i = ((unsigned int)u) << 16; return c.f;
}

typedef __attribute__((address_space(3))) void lds_void_t;
typedef __attribute__((address_space(1))) const void gvoid_t;
static __device__ __forceinline__ void gload16(const void* g, void* l) {
    __builtin_amdgcn_global_load_lds((gvoid_t*)g, (lds_void_t*)l, 16, 0, 0);
}

// ---------------------------------------------------------------------------
// fp32 -> bf16 cast: single buffer and 3-way batched (z) variants
// ---------------------------------------------------------------------------
__launch_bounds__(256)
__global__ void cvt_bf16(const float* __restrict__ in, unsigned short* __restrict__ out, int n4) {
    int i = blockIdx.x * 256 + threadIdx.x;
    if (i < n4) {
        f4 v = *(const f4*)&in[(size_t)i * 4];
        ushort4 o;
        o.x = f2bu(v[0]); o.y = f2bu(v[1]); o.z = f2bu(v[2]); o.w = f2bu(v[3]);
        *(ushort4*)&out[(size_t)i * 4] = o;
    }
}

__launch_bounds__(256)
__global__ void cvt_bf16_x3(const float* __restrict__ i0, const float* __restrict__ i1,
                            const float* __restrict__ i2,
                            unsigned short* __restrict__ o0, unsigned short* __restrict__ o1,
                            unsigned short* __restrict__ o2, int n4) {
    const int z = blockIdx.z;
    const float* in = (z == 0) ? i0 : (z == 1) ? i1 : i2;
    unsigned short* out = (z == 0) ? o0 : (z == 1) ? o1 : o2;
    int i = blockIdx.x * 256 + threadIdx.x;
    if (i < n4) {
        f4 v = *(const f4*)&in[(size_t)i * 4];
        ushort4 o;
        o.x = f2bu(v[0]); o.y = f2bu(v[1]); o.z = f2bu(v[2]); o.w = f2bu(v[3]);
        *(ushort4*)&out[(size_t)i * 4] = o;
    }
}

// ---------------------------------------------------------------------------
// Batched (z=0..2) C_z[M,N] = A_z[M,K] @ B_z[N,K]^T, bf16 out, 128x128 tile.
// ---------------------------------------------------------------------------
__launch_bounds__(256)
__global__ void gemm_mfma_b3(const unsigned short* __restrict__ A0, const unsigned short* __restrict__ A1,
                             const unsigned short* __restrict__ A2,
                             const unsigned short* __restrict__ B0, const unsigned short* __restrict__ B1,
                             const unsigned short* __restrict__ B2,
                             unsigned short* __restrict__ C0, unsigned short* __restrict__ C1,
                             unsigned short* __restrict__ C2,
                             int M, int N, int K) {
    __shared__ unsigned short Asl[128 * 32];
    __shared__ unsigned short Bsl[128 * 32];
    const int z = blockIdx.z;
    const unsigned short* A  = (z == 0) ? A0 : (z == 1) ? A1 : A2;
    const unsigned short* Bw = (z == 0) ? B0 : (z == 1) ? B1 : B2;
    unsigned short*       Cb = (z == 0) ? C0 : (z == 1) ? C1 : C2;
    const int t = threadIdx.x;
    const int lane = t & 63, w = t >> 6;
    const int wr = w >> 1, wc = w & 1;
    const int nwg = gridDim.x * gridDim.y;
    const int bid = blockIdx.y * gridDim.x + blockIdx.x;
    const int cpx = nwg >> 3;
    const int swz = (bid & 7) * cpx + (bid >> 3);
    const int row0 = (swz / gridDim.x) * 128, col0 = (swz % gridDim.x) * 128;
    const int sr0 = t >> 2, sk0 = (t & 3) * 8;
    const int lg = lane >> 4, lr = lane & 15;

    f32x4 acc[4][4] = {};
    for (int kk = 0; kk < K; kk += 32) {
        __syncthreads();
        gload16(&A [(size_t)(row0 + sr0)      * K + kk + sk0], &Asl[t * 8]);
        gload16(&A [(size_t)(row0 + sr0 + 64) * K + kk + sk0], &Asl[(t + 256) * 8]);
        gload16(&Bw[(size_t)(col0 + sr0)      * K + kk + sk0], &Bsl[t * 8]);
        gload16(&Bw[(size_t)(col0 + sr0 + 64) * K + kk + sk0], &Bsl[(t + 256) * 8]);
        __syncthreads();

        bf16x8 af[4], bfr[4];
#pragma unroll
        for (int m = 0; m < 4; ++m)
            af[m] = *(const bf16x8*)&Asl[(wr * 64 + m * 16 + lr) * 32 + lg * 8];
#pragma unroll
        for (int n = 0; n < 4; ++n)
            bfr[n] = *(const bf16x8*)&Bsl[(wc * 64 + n * 16 + lr) * 32 + lg * 8];
#pragma unroll
        for (int m = 0; m < 4; ++m)
#pragma unroll
            for (int n = 0; n < 4; ++n)
                acc[m][n] = __builtin_amdgcn_mfma_f32_16x16x32_bf16(af[m], bfr[n], acc[m][n], 0, 0, 0);
    }
#pragma unroll
    for (int m = 0; m < 4; ++m)
#pragma unroll
        for (int n = 0; n < 4; ++n)
#pragma unroll
            for (int i = 0; i < 4; ++i) {
                int r  = row0 + wr * 64 + m * 16 + lg * 4 + i;
                int cc = col0 + wc * 64 + n * 16 + lr;
                Cb[(size_t)r * N + cc] = f2bu(acc[m][n][i]);
            }
}

// ---------------------------------------------------------------------------
// Single GEMM: C[M,N] = A[M,K] @ B[N,K]^T + fp32 resid (for the out-proj).
// ---------------------------------------------------------------------------
__launch_bounds__(256)
__global__ void gemm_mfma(const unsigned short* __restrict__ A,
                          const unsigned short* __restrict__ Bw,
                          const float* __restrict__ resid,
                          float* __restrict__ Cf,
                          int M, int N, int K) {
    __shared__ unsigned short Asl[128 * 32];
    __shared__ unsigned short Bsl[128 * 32];
    const int t = threadIdx.x;
    const int lane = t & 63, w = t >> 6;
    const int wr = w >> 1, wc = w & 1;
    const int nwg = gridDim.x * gridDim.y;
    const int bid = blockIdx.y * gridDim.x + blockIdx.x;
    const int cpx = nwg >> 3;
    const int swz = (bid & 7) * cpx + (bid >> 3);
    const int row0 = (swz / gridDim.x) * 128, col0 = (swz % gridDim.x) * 128;
    const int sr0 = t >> 2, sk0 = (t & 3) * 8;
    const int lg = lane >> 4, lr = lane & 15;

    f32x4 acc[4][4] = {};
    for (int kk = 0; kk < K; kk += 32) {
        __syncthreads();
        gload16(&A [(size_t)(row0 + sr0)      * K + kk + sk0], &Asl[t * 8]);
        gload16(&A [(size_t)(row0 + sr0 + 64) * K + kk + sk0], &Asl[(t + 256) * 8]);
        gload16(&Bw[(size_t)(col0 + sr0)      * K + kk + sk0], &Bsl[t * 8]);
        gload16(&Bw[(size_t)(col0 + sr0 + 64) * K + kk + sk0], &Bsl[(t + 256) * 8]);
        __syncthreads();

        bf16x8 af[4], bfr[4];
#pragma unroll
        for (int m = 0; m < 4; ++m)
            af[m] = *(const bf16x8*)&Asl[(wr * 64 + m * 16 + lr) * 32 + lg * 8];
#pragma unroll
        for (int n = 0; n < 4; ++n)
            bfr[n] = *(const bf16x8*)&Bsl[(wc * 64 + n * 16 + lr) * 32 + lg * 8];
#pragma unroll
        for (int m = 0; m < 4; ++m)
#pragma unroll
            for (int n = 0; n < 4; ++n)
                acc[m][n] = __builtin_amdgcn_mfma_f32_16x16x32_bf16(af[m], bfr[n], acc[m][n], 0, 0, 0);
    }
#pragma unroll
    for (int m = 0; m < 4; ++m)
#pragma unroll
        for (int n = 0; n < 4; ++n)
#pragma unroll
            for (int i = 0; i < 4; ++i) {
                int r  = row0 + wr * 64 + m * 16 + lg * 4 + i;
                int cc = col0 + wc * 64 + n * 16 + lr;
                size_t off = (size_t)r * N + cc;
                Cf[off] = acc[m][n][i] + resid[off];
            }
}

// ---------------------------------------------------------------------------
// Batched (z=0..1) feat: out[m,r] = bf16(sqrt(2/R)*cos(dot(X[m],om[r]) + b[r]))
// ---------------------------------------------------------------------------
__launch_bounds__(256)
__global__ void feat_mfma_b2(const unsigned short* __restrict__ X0, const unsigned short* __restrict__ X1,
                             const unsigned short* __restrict__ om,
                             const float* __restrict__ bvec,
                             unsigned short* __restrict__ O0, unsigned short* __restrict__ O1) {
    __shared__ unsigned short Xs[2 * 64 * 32];    // 8 KB
    __shared__ unsigned short Os[2 * 256 * 32];   // 32 KB
    __shared__ unsigned short Rs[64][264];        // 33 KB repack
    const int z = blockIdx.z;
    const unsigned short* X = z ? X1 : X0;
    unsigned short* out = z ? O1 : O0;
    const int t = threadIdx.x;
    const int lane = t & 63, w = t >> 6;
    const int lg = lane >> 4, lr = lane & 15;
    const int m0 = blockIdx.x * 64;

#pragma unroll
    for (int i = 0; i < 2; ++i) {
        int cch = i * 256 + t;
        int ks = cch >> 8, row = (cch >> 2) & 63, sub = cch & 3;
        gload16(&X[(size_t)(m0 + row) * 64 + ks * 32 + sub * 8], &Xs[cch * 8]);
    }
#pragma unroll
    for (int i = 0; i < 8; ++i) {
        int cch = i * 256 + t;
        int ks = cch >> 10, r = (cch >> 2) & 255, sub = cch & 3;
        gload16(&om[(size_t)r * 64 + ks * 32 + sub * 8], &Os[cch * 8]);
    }
    __syncthreads();

    f32x4 acc[4][4] = {};
#pragma unroll
    for (int ks = 0; ks < 2; ++ks) {
        bf16x8 af[4], bfr[4];
#pragma unroll
        for (int m = 0; m < 4; ++m)
            af[m] = *(const bf16x8*)&Xs[ks * 2048 + (m * 16 + lr) * 32 + lg * 8];
#pragma unroll
        for (int n = 0; n < 4; ++n)
            bfr[n] = *(const bf16x8*)&Os[ks * 8192 + (w * 64 + n * 16 + lr) * 32 + lg * 8];
#pragma unroll
        for (int m = 0; m < 4; ++m)
#pragma unroll
            for (int n = 0; n < 4; ++n)
                acc[m][n] = __builtin_amdgcn_mfma_f32_16x16x32_bf16(af[m], bfr[n], acc[m][n], 0, 0, 0);
    }

    const float scale = 0.08838834764831845f;  // sqrt(2/256)
#pragma unroll
    for (int n = 0; n < 4; ++n) {
        const int col = w * 64 + n * 16 + lr;
        const float bb = bvec[col];
#pragma unroll
        for (int m = 0; m < 4; ++m)
#pragma unroll
            for (int ii = 0; ii < 4; ++ii)
                Rs[m * 16 + lg * 4 + ii][col] = f2bu(scale * __cosf(acc[m][n][ii] + bb));
    }
    __syncthreads();
#pragma unroll
    for (int i = 0; i < 8; ++i) {
        int cch = i * 256 + t;
        int row = cch >> 5, colc = (cch & 31) * 8;
        u16x8 vv = *(const u16x8*)&Rs[row][colc];
        *(u16x8*)&out[(size_t)(m0 + row) * 256 + colc] = vv;
    }
}

// ---------------------------------------------------------------------------
// passA (MFMA): kvT[bh][c][d][r] = sum_l kp[l][r]*vb[l][d] (bf16), ksum[r].
// ---------------------------------------------------------------------------
__launch_bounds__(256)
__global__ void passA_mfma(const unsigned short* __restrict__ kp, const unsigned short* __restrict__ vb,
                           unsigned short* __restrict__ kvT, float* __restrict__ ksum) {
    __shared__ __align__(16) unsigned short KPt[256][72];  // [r][l]
    __shared__ __align__(16) unsigned short Vt[64][72];    // [d][l]
    const int c = blockIdx.x, h = blockIdx.y, bz = blockIdx.z;
    const int t = threadIdx.x;
    const int lane = t & 63, w = t >> 6;
    const int lg = lane >> 4, lr = lane & 15;
    const int l0 = c * C_;
    const int bh = bz * H_ + h;

    {   // stage KP^T
        const int l4 = (t & 15) * 4, rs = (t >> 4) * 16;
        u16x8 row[4][2];
#pragma unroll
        for (int i = 0; i < 4; ++i) {
            const unsigned short* src = &kp[((size_t)(bz * L_ + l0 + l4 + i) * H_ + h) * R_ + rs];
            row[i][0] = *(const u16x8*)src;
            row[i][1] = *(const u16x8*)(src + 8);
        }
#pragma unroll
        for (int q = 0; q < 16; ++q) {
            u16x4 pk = { row[0][q >> 3][q & 7], row[1][q >> 3][q & 7],
                         row[2][q >> 3][q & 7], row[3][q >> 3][q & 7] };
            *(u16x4*)&KPt[rs + q][l4] = pk;
        }
    }
    {   // stage V^T (bf16 pass-through)
        const int d4 = (t & 15) * 4, ls = (t >> 4) * 4;
        u16x4 x[4];
#pragma unroll
        for (int i = 0; i < 4; ++i)
            x[i] = *(const u16x4*)&vb[(size_t)(bz * L_ + l0 + ls + i) * DM_ + h * 64 + d4];
#pragma unroll
        for (int q = 0; q < 4; ++q) {
            u16x4 pk = { x[0][q], x[1][q], x[2][q], x[3][q] };
            *(u16x4*)&Vt[d4 + q][ls] = pk;
        }
    }
    __syncthreads();

    f32x4 acc[4][4] = {};
#pragma unroll
    for (int ks = 0; ks < 2; ++ks) {
        bf16x8 af[4], bfr[4];
#pragma unroll
        for (int m = 0; m < 4; ++m)
            af[m] = *(const bf16x8*)&KPt[64 * w + 16 * m + lr][ks * 32 + lg * 8];
#pragma unroll
        for (int n = 0; n < 4; ++n)
            bfr[n] = *(const bf16x8*)&Vt[16 * n + lr][ks * 32 + lg * 8];
#pragma unroll
        for (int m = 0; m < 4; ++m)
#pragma unroll
            for (int n = 0; n < 4; ++n)
                acc[m][n] = __builtin_amdgcn_mfma_f32_16x16x32_bf16(af[m], bfr[n], acc[m][n], 0, 0, 0);
    }
    size_t sbase = ((size_t)(bh * NC_ + c)) * 64 * R_;
#pragma unroll
    for (int n = 0; n < 4; ++n)
#pragma unroll
        for (int m = 0; m < 4; ++m) {
            int d = 16 * n + lr;
            int r = 64 * w + 16 * m + lg * 4;
            u16x4 pk = { f2bu(acc[m][n][0]), f2bu(acc[m][n][1]),
                         f2bu(acc[m][n][2]), f2bu(acc[m][n][3]) };
            *(u16x4*)&kvT[sbase + (size_t)d * R_ + r] = pk;
        }
    {
        float s = 0.f;
#pragma unroll
        for (int j = 0; j < 8; ++j) {
            u16x8 vv = *(const u16x8*)&KPt[t][j * 8];
#pragma unroll
            for (int q = 0; q < 8; ++q) s += bu2f(vv[q]);
        }
        ksum[((size_t)(bh * NC_ + c)) * R_ + t] = s;
    }
}

// ---------------------------------------------------------------------------
// passB: exclusive prefix over chunks of kvT ([bh][c][d][r]) and ksum.
// ---------------------------------------------------------------------------
__launch_bounds__(256)
__global__ void passB_chain(unsigned short* __restrict__ kvT, float* __restrict__ ksum) {
    const int d = blockIdx.x, h = blockIdx.y, bz = blockIdx.z;
    const int t = threadIdx.x;
    const int bh = bz * H_ + h;
    size_t base = ((size_t)bh * NC_ * 64 + d) * R_ + t;
    const size_t cstride = (size_t)64 * R_;
    float run = 0.f;
    for (int c = 0; c < NC_; ++c) {
        size_t idx = base + (size_t)c * cstride;
        float tmp = bu2f(kvT[idx]);
        kvT[idx] = f2bu(run);
        run += tmp;
    }
    if (d == 0) {
        float rz = 0.f;
        for (int c = 0; c < NC_; ++c) {
            size_t idx = ((size_t)bh * NC_ + c) * R_ + t;
            float tmp = ksum[idx];
            ksum[idx] = rz;
            rz += tmp;
        }
    }
}

// ---------------------------------------------------------------------------
// passC (MFMA): prologue async Sl prefetch (pre-swizzled source); scores with
// register-hoisted bk; Spref from LDS + zu fragments; AV+den; bf16 out.
// ---------------------------------------------------------------------------
__launch_bounds__(256)
__global__ void passC_mfma(const unsigned short* __restrict__ qp, const unsigned short* __restrict__ kp,
                           const unsigned short* __restrict__ vb, const unsigned short* __restrict__ kvT,
                           const float* __restrict__ zpref, unsigned short* __restrict__ attnb) {
    __shared__ __align__(16) unsigned short Sl[64 * 256];  // 32 KB, swizzled kvT tile
    __shared__ __align__(16) unsigned short Vt[80][72];    // [d][l], row64=ones
    __shared__ __align__(16) unsigned short As[64][72];    // masked scores

    const int c = blockIdx.x, h = blockIdx.y, bz = blockIdx.z;
    const int t = threadIdx.x;
    const int lane = t & 63, w = t >> 6;
    const int lg = lane >> 4, lr = lane & 15;
    const int l0 = c * C_;
    const int bh = bz * H_ + h;
    const size_t sbase = ((size_t)(bh * NC_ + c)) * 64 * R_;
    const size_t zbase = ((size_t)(bh * NC_ + c)) * R_;

#pragma unroll
    for (int i = 0; i < 8; ++i) {
        int idx = i * 256 + t;
        int row = idx >> 5, s = idx & 31;
        gload16(&kvT[sbase + (size_t)row * R_ + ((s ^ (row & 7)) << 3)], &Sl[idx * 8]);
    }

    {   // stage V^T (bf16 pass-through)
        const int d4 = (t & 15) * 4, ls = (t >> 4) * 4;
        u16x4 x[4];
#pragma unroll
        for (int i = 0; i < 4; ++i)
            x[i] = *(const u16x4*)&vb[(size_t)(bz * L_ + l0 + ls + i) * DM_ + h * 64 + d4];
#pragma unroll
        for (int q = 0; q < 4; ++q) {
            u16x4 pk = { x[0][q], x[1][q], x[2][q], x[3][q] };
            *(u16x4*)&Vt[d4 + q][ls] = pk;
        }
    }
    if (t < 16) {
        u16x4 ones = { 0x3F80, 0x3F80, 0x3F80, 0x3F80 };
        *(u16x4*)&Vt[64][t * 4] = ones;
    }

    const size_t qrow = ((size_t)(bz * L_ + l0 + 16 * w + lr) * H_ + h) * R_;
    bf16x8 aq[8];
#pragma unroll
    for (int ks = 0; ks < 8; ++ks) aq[ks] = *(const bf16x8*)&qp[qrow + ks * 32 + lg * 8];

    // ---- scores: two half-hoists of 16 bk fragments each ----
    f32x4 sacc[4] = {};
#pragma unroll
    for (int half = 0; half < 2; ++half) {
        bf16x8 bk[4][4];
#pragma unroll
        for (int k2 = 0; k2 < 4; ++k2)
#pragma unroll
            for (int n = 0; n < 4; ++n)
                bk[k2][n] = *(const bf16x8*)&kp[((size_t)(bz * L_ + l0 + 16 * n + lr) * H_ + h) * R_
                                                + (half * 4 + k2) * 32 + lg * 8];
        __builtin_amdgcn_s_setprio(1);
#pragma unroll
        for (int k2 = 0; k2 < 4; ++k2)
#pragma unroll
            for (int n = 0; n < 4; ++n)
                sacc[n] = __builtin_amdgcn_mfma_f32_16x16x32_bf16(aq[half * 4 + k2], bk[k2][n], sacc[n], 0, 0, 0);
        __builtin_amdgcn_s_setprio(0);
    }
#pragma unroll
    for (int n = 0; n < 4; ++n)
#pragma unroll
        for (int ii = 0; ii < 4; ++ii) {
            int i_loc = 16 * w + lg * 4 + ii;
            int j_loc = 16 * n + lr;
            As[i_loc][j_loc] = (j_loc <= i_loc) ? f2bu(sacc[n][ii]) : (unsigned short)0;
        }

    u16x8 zu[8];
#pragma unroll
    for (int ks = 0; ks < 8; ++ks) {
        f4 z0 = *(const f4*)&zpref[zbase + ks * 32 + lg * 8];
        f4 z1 = *(const f4*)&zpref[zbase + ks * 32 + lg * 8 + 4];
        zu[ks] = u16x8{ f2bu(z0[0]), f2bu(z0[1]), f2bu(z0[2]), f2bu(z0[3]),
                        f2bu(z1[0]), f2bu(z1[1]), f2bu(z1[2]), f2bu(z1[3]) };
    }
    __syncthreads();

    f32x4 oacc[4] = {};
    f32x4 dacc = {};
    __builtin_amdgcn_s_setprio(1);
#pragma unroll
    for (int ks = 0; ks < 8; ++ks) {
#pragma unroll
        for (int n = 0; n < 4; ++n) {
            int row = 16 * n + lr;
            int slot = (ks * 4 + lg) ^ (lr & 7);
            bf16x8 bs = *(const bf16x8*)&Sl[row * 256 + slot * 8];
            oacc[n] = __builtin_amdgcn_mfma_f32_16x16x32_bf16(aq[ks], bs, oacc[n], 0, 0, 0);
        }
        dacc = __builtin_amdgcn_mfma_f32_16x16x32_bf16(aq[ks], *(bf16x8*)&zu[ks], dacc, 0, 0, 0);
    }

    f32x4 racc = {};
#pragma unroll
    for (int ks = 0; ks < 2; ++ks) {
        bf16x8 aa = *(const bf16x8*)&As[16 * w + lr][ks * 32 + lg * 8];
#pragma unroll
        for (int n = 0; n < 4; ++n) {
            bf16x8 bv = *(const bf16x8*)&Vt[16 * n + lr][ks * 32 + lg * 8];
            oacc[n] = __builtin_amdgcn_mfma_f32_16x16x32_bf16(aa, bv, oacc[n], 0, 0, 0);
        }
        bf16x8 b4 = *(const bf16x8*)&Vt[64 + lr][ks * 32 + lg * 8];
        racc = __builtin_amdgcn_mfma_f32_16x16x32_bf16(aa, b4, racc, 0, 0, 0);
    }
    __builtin_amdgcn_s_setprio(0);

#pragma unroll
    for (int ii = 0; ii < 4; ++ii) {
        float rs_ = __shfl(racc[ii], lane & 48, 64);
        float den = rs_ + dacc[ii];
        float inv = 1.f / (fmaxf(den, 1e-6f) + 1e-6f);
#pragma unroll
        for (int n = 0; n < 4; ++n)
            attnb[(size_t)(bz * L_ + l0 + 16 * w + lg * 4 + ii) * DM_ + h * 64 + 16 * n + lr] =
                f2bu(oacc[n][ii] * inv);
    }
}

// ---------------------------------------------------------------------------
// In-place row LayerNorm over last dim (1024), eps=1e-5.
// ---------------------------------------------------------------------------
__launch_bounds__(256)
__global__ void ln_kernel(float* __restrict__ io, const float* __restrict__ gamma,
                          const float* __restrict__ beta) {
    __shared__ float wsum[4], wsum2[4];
    const int row = blockIdx.x;
    const int t = threadIdx.x;
    f4 x = *(const f4*)&io[(size_t)row * DM_ + t * 4];
    float s  = x[0] + x[1] + x[2] + x[3];
    float s2 = x[0]*x[0] + x[1]*x[1] + x[2]*x[2] + x[3]*x[3];
#pragma unroll
    for (int o = 32; o > 0; o >>= 1) {
        s  += __shfl_down(s, o);
        s2 += __shfl_down(s2, o);
    }
    if ((t & 63) == 0) { wsum[t >> 6] = s; wsum2[t >> 6] = s2; }
    __syncthreads();
    s  = wsum[0]  + wsum[1]  + wsum[2]  + wsum[3];
    s2 = wsum2[0] + wsum2[1] + wsum2[2] + wsum2[3];
    const float m = s * (1.f / DM_);
    const float var = s2 * (1.f / DM_) - m * m;
    const float rstd = rsqrtf(var + 1e-5f);
    f4 g  = *(const f4*)&gamma[t * 4];
    f4 bb = *(const f4*)&beta[t * 4];
    f4 o = (x - m) * rstd * g + bb;
    *(f4*)&io[(size_t)row * DM_ + t * 4] = o;
}

// ---------------------------------------------------------------------------
// Workspace (226 MB), staged aliasing (audited):
//  persistent: qp[0,64) kp[64,128) kvT[128,192) vb[192,208) attnb[208,224) ksum[224,226)
//  QKV phase:  aq[0,16) ak[16,32) av[32,48) wq[48,50) wk[50,52) wv[52,54)
//              outputs qx[128,144) kx[144,160) vb[192,208)
//  om_bf at [208,208.07) (attnb slot; dead before passC writes attnb)
//  feat: reads qx/kx+om, writes qp[0,64) (aq/ak/av/w dead) + kp[64,128)
//  passA: writes kvT[128,192) (qx/kx dead) ; wo_bf[64,66) after passC (kp dead)
// ---------------------------------------------------------------------------
extern "C" void kernel_launch(void* const* d_in, const int* in_sizes, int n_in,
                              void* d_out, int out_size, void* d_ws, size_t ws_size,
                              hipStream_t stream) {
    const float* pre_q = (const float*)d_in[0];
    const float* pre_k = (const float*)d_in[1];
    const float* pre_v = (const float*)d_in[2];
    const float* wq    = (const float*)d_in[3];
    const float* wk    = (const float*)d_in[4];
    const float* wv    = (const float*)d_in[5];
    const float* wo    = (const float*)d_in[6];
    const float* gamma = (const float*)d_in[7];
    const float* beta  = (const float*)d_in[8];
    const float* omega = (const float*)d_in[9];
    const float* bvec  = (const float*)d_in[10];

    const size_t NEED = 226ull << 20;
    if (ws_size < NEED) return;

    char* w = (char*)d_ws;
    unsigned short* qp    = (unsigned short*)(w);
    unsigned short* kp    = (unsigned short*)(w + (64ull << 20));
    unsigned short* kvT   = (unsigned short*)(w + (128ull << 20));
    unsigned short* vb    = (unsigned short*)(w + (192ull << 20));
    unsigned short* attnb = (unsigned short*)(w + (208ull << 20));
    float*          ksum  = (float*)(w + (224ull << 20));
    // transients
    unsigned short* aq    = (unsigned short*)(w);                   // [0,16)
    unsigned short* ak    = (unsigned short*)(w + (16ull << 20));
    unsigned short* av    = (unsigned short*)(w + (32ull << 20));
    unsigned short* wq_bf = (unsigned short*)(w + (48ull << 20));
    unsigned short* wk_bf = (unsigned short*)(w + (50ull << 20));
    unsigned short* wv_bf = (unsigned short*)(w + (52ull << 20));
    unsigned short* qx    = (unsigned short*)(w + (128ull << 20));  // kvT slot
    unsigned short* kx    = (unsigned short*)(w + (144ull << 20));
    unsigned short* om_bf = (unsigned short*)(w + (208ull << 20));  // attnb slot
    unsigned short* wo_bf = (unsigned short*)(w + (64ull << 20));   // kp slot, post-passC
    float*          outb  = (float*)d_out;

    const int n4_big = M_ * DM_ / 4;
    const int n4_w   = DM_ * DM_ / 4;
    const int n4_om  = R_ * D_ / 4;
    dim3 gg3(DM_ / 128, M_ / 128, 3);
    dim3 gg(DM_ / 128, M_ / 128);

    // casts (batched big inputs; weights + omega individually)
    cvt_bf16_x3<<<dim3((n4_big + 255) / 256, 1, 3), 256, 0, stream>>>(
        pre_q, pre_k, pre_v, aq, ak, av, n4_big);
    cvt_bf16_x3<<<dim3((n4_w + 255) / 256, 1, 3), 256, 0, stream>>>(
        wq, wk, wv, wq_bf, wk_bf, wv_bf, n4_w);
    cvt_bf16<<<(n4_om + 255) / 256, 256, 0, stream>>>(omega, om_bf, n4_om);

    // batched QKV projection (1536 blocks)
    gemm_mfma_b3<<<gg3, 256, 0, stream>>>(aq, ak, av, wq_bf, wk_bf, wv_bf,
                                          qx, kx, vb, M_, DM_, DM_);
    // batched feature maps (4096 blocks)
    feat_mfma_b2<<<dim3(M2_ / 64, 1, 2), 256, 0, stream>>>(qx, kx, om_bf, bvec, qp, kp);

    passA_mfma<<<dim3(NC_, H_, B_), 256, 0, stream>>>(kp, vb, kvT, ksum);
    passB_chain<<<dim3(64, H_, B_), 256, 0, stream>>>(kvT, ksum);
    passC_mfma<<<dim3(NC_, H_, B_), 256, 0, stream>>>(qp, kp, vb, kvT, ksum, attnb);

    cvt_bf16<<<(n4_w + 255) / 256, 256, 0, stream>>>(wo, wo_bf, n4_w);
    gemm_mfma<<<gg, 256, 0, stream>>>(attnb, wo_bf, pre_q, outb, M_, DM_, DM_);
    ln_kernel<<<M_, 256, 0, stream>>>(outb, gamma, beta);
}